// Round 8
// baseline (1479.149 us; speedup 1.0000x reference)
//
#include <hip/hip_runtime.h>
#include <math.h>

#define DEV __device__ __forceinline__
DEV float frelu(float x) { return x > 0.f ? x : 0.f; }

typedef float f4 __attribute__((ext_vector_type(4)));

// ===========================================================================
// Stage 1 (pixel-per-lane): conv 3->32 relu -> conv 32->32 relu ; e1 raw
// score (tanh dropped: monotonic, only ordering used) ; pool5 -> x1p.
// Block = one (b,h) row, 128 threads, lanes 0..99 = pool groups. All weights
// block-uniform -> SGPR; zero LDS, zero shuffles, zero barriers.
// ===========================================================================
__global__ __launch_bounds__(128) void k_s1(
    const float* __restrict__ x,
    const float* __restrict__ w1, const float* __restrict__ b1,
    const float* __restrict__ w2, const float* __restrict__ b2,
    const float* __restrict__ aW, const float* __restrict__ ab,
    float* __restrict__ x1p, float* __restrict__ e1)
{
    int r = blockIdx.x;                  // 3200 rows = (b*50+h)
    int h = r % 50;
    int pw = threadIdx.x;
    if (pw >= 100) return;
    const float* xrow = x + (size_t)r * 1500;

    float vmax[32];
#pragma unroll
    for (int o = 0; o < 32; ++o) vmax[o] = 0.f;

#pragma unroll 1
    for (int j = 0; j < 5; ++j) {
        int w = pw * 5 + j;
        float x0 = xrow[w * 3 + 0], x1v = xrow[w * 3 + 1], x2v = xrow[w * 3 + 2];
        float v1[32];
#pragma unroll
        for (int o = 0; o < 32; ++o)
            v1[o] = frelu(fmaf(x0, w1[o], fmaf(x1v, w1[32 + o], fmaf(x2v, w1[64 + o], b1[o]))));
        float v2[32];
#pragma unroll
        for (int o = 0; o < 32; ++o) v2[o] = b2[o];
#pragma unroll
        for (int i = 0; i < 32; ++i) {
            float a = v1[i];
#pragma unroll
            for (int o = 0; o < 32; ++o) v2[o] = fmaf(a, w2[i * 32 + o], v2[o]);
        }
        float e = ab[h * 500 + w];
#pragma unroll
        for (int o = 0; o < 32; ++o) {
            float t = frelu(v2[o]);
            vmax[o] = fmaxf(vmax[o], t);
            e = fmaf(t, aW[h * 32 + o], e);
        }
        e1[(size_t)r * 500 + w] = e;     // raw score (tanh monotone)
    }
    float* dst = x1p + ((size_t)r * 100 + pw) * 32;
#pragma unroll
    for (int q = 0; q < 8; ++q)
        *(f4*)(dst + q * 4) = *(f4*)&vmax[q * 4];
}

// ===========================================================================
// Stage 2 (pixel-per-lane): conv 32->64 relu -> conv 64->64 relu ; e2 raw ;
// pool5 -> x2p. Block = 5 rows, 128 threads, lane -> (row_local, pool group).
// v1 staged per-lane in LDS (stride 65: bank=(l+i)%32, 2-way = free) so the
// conv2 i-loop stays runtime-indexed (small I$) with static v2[o] accums.
// aW rows staged in LDS (per-lane h).
// ===========================================================================
__global__ __launch_bounds__(128) void k_s2(
    const float* __restrict__ x1p,
    const float* __restrict__ w1, const float* __restrict__ b1,
    const float* __restrict__ w2, const float* __restrict__ b2,
    const float* __restrict__ aW, const float* __restrict__ ab,
    float* __restrict__ x2p, float* __restrict__ e2)
{
    __shared__ float v1l[100 * 65];
    __shared__ float aWs[5 * 64];
    int tid = threadIdx.x;
    int r0 = blockIdx.x * 5;             // 640 blocks
    for (int idx = tid; idx < 320; idx += 128) {
        int rl = idx >> 6, o = idx & 63;
        aWs[idx] = aW[((r0 + rl) % 50) * 64 + o];
    }
    __syncthreads();
    if (tid >= 100) return;
    int rl = tid / 20, pw = tid % 20;
    int r = r0 + rl;
    int h = r % 50;
    float* vl = &v1l[tid * 65];

    float vmax[64];
#pragma unroll
    for (int o = 0; o < 64; ++o) vmax[o] = 0.f;

#pragma unroll 1
    for (int j = 0; j < 5; ++j) {
        int w = pw * 5 + j;
        const float* in = x1p + ((size_t)r * 100 + w) * 32;
        float v1[64];
#pragma unroll
        for (int o = 0; o < 64; ++o) v1[o] = b1[o];
#pragma unroll 1
        for (int c = 0; c < 8; ++c) {
            f4 a4 = *(const f4*)(in + c * 4);
#pragma unroll
            for (int o = 0; o < 64; ++o) v1[o] = fmaf(a4.x, w1[(c * 4 + 0) * 64 + o], v1[o]);
#pragma unroll
            for (int o = 0; o < 64; ++o) v1[o] = fmaf(a4.y, w1[(c * 4 + 1) * 64 + o], v1[o]);
#pragma unroll
            for (int o = 0; o < 64; ++o) v1[o] = fmaf(a4.z, w1[(c * 4 + 2) * 64 + o], v1[o]);
#pragma unroll
            for (int o = 0; o < 64; ++o) v1[o] = fmaf(a4.w, w1[(c * 4 + 3) * 64 + o], v1[o]);
        }
#pragma unroll
        for (int o = 0; o < 64; ++o) vl[o] = frelu(v1[o]);

        float v2[64];
#pragma unroll
        for (int o = 0; o < 64; ++o) v2[o] = b2[o];
#pragma unroll 4
        for (int i = 0; i < 64; ++i) {
            float a = vl[i];
#pragma unroll
            for (int o = 0; o < 64; ++o) v2[o] = fmaf(a, w2[i * 64 + o], v2[o]);
        }
        float e = ab[h * 100 + w];
#pragma unroll
        for (int o = 0; o < 64; ++o) {
            float t = frelu(v2[o]);
            vmax[o] = fmaxf(vmax[o], t);
            e = fmaf(t, aWs[rl * 64 + o], e);
        }
        e2[(size_t)r * 100 + w] = e;     // raw score
    }
    float* dst = x2p + ((size_t)r * 20 + pw) * 64;
#pragma unroll
    for (int q = 0; q < 16; ++q)
        *(f4*)(dst + q * 4) = *(f4*)&vmax[q * 4];
}

// ===========================================================================
// Stage 3 (channel-mapped WREG): conv 64->128 relu -> conv 128->128 relu ;
// e3 raw ; pool4 -> x3p. NG3=8, grid 1000 (more waves for latency hiding);
// split accumulators to break dependent-FMA chains.
// ===========================================================================
#define NG3 8
__global__ __launch_bounds__(256) void k_s3(
    const float* __restrict__ x2p,
    const float* __restrict__ w1, const float* __restrict__ b1,
    const float* __restrict__ w2, const float* __restrict__ b2,
    const float* __restrict__ aW, const float* __restrict__ ab,
    float* __restrict__ x3p, float* __restrict__ e3)
{
    __shared__ float v1s[2][128];
    __shared__ float epart[2][2];
    int tid = threadIdx.x;
    int wv = tid >> 6, lane = tid & 63;
    int slot = wv >> 1, oh = wv & 1;
    int o = oh * 64 + lane;
    int gs = blockIdx.x * 2 + slot;              // 2000 slots

    float W1[64];
#pragma unroll
    for (int i = 0; i < 64; ++i) W1[i] = w1[i * 128 + o];
    float W2[128];
#pragma unroll
    for (int i = 0; i < 128; ++i) W2[i] = w2[i * 128 + o];
    float B1 = b1[o], B2 = b2[o];

#pragma unroll 1
    for (int i = 0; i < NG3; ++i) {
        int g = gs * NG3 + i;                    // 0..15999
        int b = g / 250, r = g % 250, h = r / 5, pw = r % 5;
        float AWo = aW[h * 128 + o];
        float vmax = 0.f;
#pragma unroll 1
        for (int j = 0; j < 4; ++j) {
            int w = pw * 4 + j;
            const float* in = x2p + (size_t)((b * 50 + h) * 20 + w) * 64;
            float a1a = B1, a1b = 0.f;
#pragma unroll
            for (int q = 0; q < 64; q += 8) {
                float4 a4 = *(const float4*)&in[q];
                float4 b4 = *(const float4*)&in[q + 4];
                a1a = fmaf(a4.x, W1[q + 0], a1a);
                a1b = fmaf(a4.y, W1[q + 1], a1b);
                a1a = fmaf(a4.z, W1[q + 2], a1a);
                a1b = fmaf(a4.w, W1[q + 3], a1b);
                a1a = fmaf(b4.x, W1[q + 4], a1a);
                a1b = fmaf(b4.y, W1[q + 5], a1b);
                a1a = fmaf(b4.z, W1[q + 6], a1a);
                a1b = fmaf(b4.w, W1[q + 7], a1b);
            }
            v1s[slot][o] = frelu(a1a + a1b);
            __syncthreads();
            float a2a = B2, a2b = 0.f, a2c = 0.f, a2d = 0.f;
#pragma unroll
            for (int q = 0; q < 128; q += 8) {
                float4 a4 = *(const float4*)&v1s[slot][q];
                float4 b4 = *(const float4*)&v1s[slot][q + 4];
                a2a = fmaf(a4.x, W2[q + 0], a2a);
                a2b = fmaf(a4.y, W2[q + 1], a2b);
                a2c = fmaf(a4.z, W2[q + 2], a2c);
                a2d = fmaf(a4.w, W2[q + 3], a2d);
                a2a = fmaf(b4.x, W2[q + 4], a2a);
                a2b = fmaf(b4.y, W2[q + 5], a2b);
                a2c = fmaf(b4.z, W2[q + 6], a2c);
                a2d = fmaf(b4.w, W2[q + 7], a2d);
            }
            float t = frelu((a2a + a2b) + (a2c + a2d));
            vmax = fmaxf(vmax, t);
            float ep = t * AWo;
            ep += __shfl_xor(ep, 1, 64);
            ep += __shfl_xor(ep, 2, 64);
            ep += __shfl_xor(ep, 4, 64);
            ep += __shfl_xor(ep, 8, 64);
            ep += __shfl_xor(ep, 16, 64);
            ep += __shfl_xor(ep, 32, 64);
            if (lane == 0) epart[slot][oh] = ep;
            __syncthreads();
            if (lane == 0 && oh == 0)
                e3[(b * 50 + h) * 20 + w] = epart[slot][0] + epart[slot][1] + ab[h * 20 + w];
        }
        x3p[(size_t)g * 128 + o] = vmax;
    }
}

// ===========================================================================
// Top-k (k=10, value desc, tie -> lower index) + feature recompute.
// ===========================================================================
__global__ __launch_bounds__(64) void k_t1(
    const float* __restrict__ e1, const float* __restrict__ x,
    const float* __restrict__ w1, const float* __restrict__ b1,
    const float* __restrict__ w2, const float* __restrict__ b2,
    float* __restrict__ z)
{
    int blk = blockIdx.x; int b = blk / 50; int h = blk % 50;
    int lane = threadIdx.x;
    const float* er = e1 + (b * 50 + h) * 500;
    float ev0 = er[lane];
    float ev1 = er[64 + lane];
    float ev2 = er[128 + lane];
    float ev3 = er[192 + lane];
    float ev4 = er[256 + lane];
    float ev5 = er[320 + lane];
    float ev6 = er[384 + lane];
    float ev7 = (448 + lane < 500) ? er[448 + lane] : -1e30f;

    for (int k = 0; k < 10; ++k) {
        float bv = ev0; int bi = lane;
        if (ev1 > bv) { bv = ev1; bi = 64 + lane; }
        if (ev2 > bv) { bv = ev2; bi = 128 + lane; }
        if (ev3 > bv) { bv = ev3; bi = 192 + lane; }
        if (ev4 > bv) { bv = ev4; bi = 256 + lane; }
        if (ev5 > bv) { bv = ev5; bi = 320 + lane; }
        if (ev6 > bv) { bv = ev6; bi = 384 + lane; }
        if (ev7 > bv) { bv = ev7; bi = 448 + lane; }
#pragma unroll
        for (int d = 1; d < 64; d <<= 1) {
            float ov = __shfl_xor(bv, d, 64); int oi = __shfl_xor(bi, d, 64);
            if (ov > bv || (ov == bv && oi < bi)) { bv = ov; bi = oi; }
        }
        bool me = (bi & 63) == lane; int cs = bi >> 6;
        if (me && cs == 0) ev0 = -1e30f;
        if (me && cs == 1) ev1 = -1e30f;
        if (me && cs == 2) ev2 = -1e30f;
        if (me && cs == 3) ev3 = -1e30f;
        if (me && cs == 4) ev4 = -1e30f;
        if (me && cs == 5) ev5 = -1e30f;
        if (me && cs == 6) ev6 = -1e30f;
        if (me && cs == 7) ev7 = -1e30f;

        const float* px = x + (size_t)((b * 50 + h) * 500 + bi) * 3;
        float x0 = px[0], x1v = px[1], x2v = px[2];
        int o = lane & 31;
        float v1 = frelu(fmaf(x0, w1[o], fmaf(x1v, w1[32 + o], fmaf(x2v, w1[64 + o], b1[o]))));
        float v2 = b2[o];
#pragma unroll 8
        for (int i = 0; i < 32; ++i) v2 = fmaf(__shfl(v1, i, 64), w2[i * 32 + o], v2);
        if (lane < 32) z[(size_t)b * 112000 + h * 320 + k * 32 + o] = frelu(v2);
    }
}

__global__ __launch_bounds__(64) void k_t2(
    const float* __restrict__ e2, const float* __restrict__ x1p,
    const float* __restrict__ w1, const float* __restrict__ b1,
    const float* __restrict__ w2, const float* __restrict__ b2,
    float* __restrict__ z)
{
    int blk = blockIdx.x; int b = blk / 50; int h = blk % 50;
    int lane = threadIdx.x;
    const float* er = e2 + (b * 50 + h) * 100;
    float ev0 = er[lane];
    float ev1 = (64 + lane < 100) ? er[64 + lane] : -1e30f;

    for (int k = 0; k < 10; ++k) {
        float bv = ev0; int bi = lane;
        if (ev1 > bv) { bv = ev1; bi = 64 + lane; }
#pragma unroll
        for (int d = 1; d < 64; d <<= 1) {
            float ov = __shfl_xor(bv, d, 64); int oi = __shfl_xor(bi, d, 64);
            if (ov > bv || (ov == bv && oi < bi)) { bv = ov; bi = oi; }
        }
        bool me = (bi & 63) == lane; int cs = bi >> 6;
        if (me && cs == 0) ev0 = -1e30f;
        if (me && cs == 1) ev1 = -1e30f;

        const float* in = x1p + (size_t)((b * 50 + h) * 100 + bi) * 32;
        float v1p0 = b1[lane], v1p1 = 0.f;
#pragma unroll 8
        for (int i = 0; i < 32; i += 2) {
            v1p0 = fmaf(in[i], w1[i * 64 + lane], v1p0);
            v1p1 = fmaf(in[i + 1], w1[(i + 1) * 64 + lane], v1p1);
        }
        float v1 = frelu(v1p0 + v1p1);
        float v2p0 = b2[lane], v2p1 = 0.f;
#pragma unroll 8
        for (int i = 0; i < 64; i += 2) {
            v2p0 = fmaf(__shfl(v1, i, 64), w2[i * 64 + lane], v2p0);
            v2p1 = fmaf(__shfl(v1, i + 1, 64), w2[(i + 1) * 64 + lane], v2p1);
        }
        z[(size_t)b * 112000 + 16000 + h * 640 + k * 64 + lane] = frelu(v2p0 + v2p1);
    }
}

__global__ __launch_bounds__(64) void k_t3(
    const float* __restrict__ e3, const float* __restrict__ x2p,
    const float* __restrict__ w1, const float* __restrict__ b1,
    const float* __restrict__ w2, const float* __restrict__ b2,
    float* __restrict__ z)
{
    int blk = blockIdx.x; int b = blk / 50; int h = blk % 50;
    int lane = threadIdx.x;
    const float* er = e3 + (b * 50 + h) * 20;
    float ev0 = (lane < 20) ? er[lane] : -1e30f;

    for (int k = 0; k < 10; ++k) {
        float bv = ev0; int bi = lane;
#pragma unroll
        for (int d = 1; d < 64; d <<= 1) {
            float ov = __shfl_xor(bv, d, 64); int oi = __shfl_xor(bi, d, 64);
            if (ov > bv || (ov == bv && oi < bi)) { bv = ov; bi = oi; }
        }
        if (bi == lane) ev0 = -1e30f;
        const float* in = x2p + (size_t)((b * 50 + h) * 20 + bi) * 64;
        float v1a0 = b1[lane], v1a1 = 0.f, v1b0 = b1[lane + 64], v1b1 = 0.f;
#pragma unroll 8
        for (int i = 0; i < 64; i += 2) {
            float a0 = in[i], a1 = in[i + 1];
            v1a0 = fmaf(a0, w1[i * 128 + lane], v1a0);
            v1b0 = fmaf(a0, w1[i * 128 + lane + 64], v1b0);
            v1a1 = fmaf(a1, w1[(i + 1) * 128 + lane], v1a1);
            v1b1 = fmaf(a1, w1[(i + 1) * 128 + lane + 64], v1b1);
        }
        float v1a = frelu(v1a0 + v1a1), v1b = frelu(v1b0 + v1b1);
        float v2a0 = b2[lane], v2a1 = 0.f, v2b0 = b2[lane + 64], v2b1 = 0.f;
#pragma unroll 8
        for (int i = 0; i < 64; i += 2) {
            float s0 = __shfl(v1a, i, 64), s1 = __shfl(v1a, i + 1, 64);
            v2a0 = fmaf(s0, w2[i * 128 + lane], v2a0);
            v2b0 = fmaf(s0, w2[i * 128 + lane + 64], v2b0);
            v2a1 = fmaf(s1, w2[(i + 1) * 128 + lane], v2a1);
            v2b1 = fmaf(s1, w2[(i + 1) * 128 + lane + 64], v2b1);
        }
#pragma unroll 8
        for (int i = 0; i < 64; i += 2) {
            float s0 = __shfl(v1b, i, 64), s1 = __shfl(v1b, i + 1, 64);
            v2a0 = fmaf(s0, w2[(i + 64) * 128 + lane], v2a0);
            v2b0 = fmaf(s0, w2[(i + 64) * 128 + lane + 64], v2b0);
            v2a1 = fmaf(s1, w2[(i + 65) * 128 + lane], v2a1);
            v2b1 = fmaf(s1, w2[(i + 65) * 128 + lane + 64], v2b1);
        }
        size_t base = (size_t)b * 112000 + 48000 + h * 1280 + k * 128;
        z[base + lane] = frelu(v2a0 + v2a1);
        z[base + lane + 64] = frelu(v2b0 + v2b1);
    }
}

// ===========================================================================
// k_zt: transpose z[m][f] (f<112000) -> zT[f][m]
// ===========================================================================
__global__ __launch_bounds__(256) void k_zt(const float* __restrict__ z, float* __restrict__ zT)
{
    __shared__ float t[64][65];
    int f0 = blockIdx.x * 64;                // 1750 blocks
    int tid = threadIdx.x;
    int fl = tid & 63, q = tid >> 6;
#pragma unroll
    for (int rr = 0; rr < 16; ++rr) {
        int m = q * 16 + rr;
        t[m][fl] = z[(size_t)m * 112000 + f0 + fl];
    }
    __syncthreads();
    int m2 = tid & 63;
#pragma unroll
    for (int rr = 0; rr < 16; ++rr) {
        int fl2 = q * 16 + rr;
        zT[(size_t)(f0 + fl2) * 64 + m2] = t[m2][fl2];
    }
}

// ===========================================================================
// k_xf: x3p (B,H,5,128) -> zT rows 112000 + c*250 + h*5 + pw, layout [f][m]
// ===========================================================================
__global__ __launch_bounds__(256) void k_xf(const float* __restrict__ x3p, float* __restrict__ zT)
{
    __shared__ float t[64][129];
    int blk = blockIdx.x;                    // 250
    int h = blk / 5, pw = blk % 5;
    int tid = threadIdx.x;
    for (int idx = tid; idx < 64 * 128; idx += 256) {
        int m = idx >> 7, c = idx & 127;
        t[m][c] = x3p[(size_t)((m * 50 + h) * 5 + pw) * 128 + c];
    }
    __syncthreads();
    for (int idx = tid; idx < 64 * 128; idx += 256) {
        int c = idx >> 6, m = idx & 63;
        zT[(size_t)(112000 + c * 250 + h * 5 + pw) * 64 + m] = t[m][c];
    }
}

// ===========================================================================
// fc1 GEMM — double-buffered LDS tile (unchanged from R7; <345 us proven).
// Block tile 64m x 256n, BK=16, thread tile 8m x 8n, grid (4, 250).
// ===========================================================================
__global__ __launch_bounds__(256, 4) void k_gemm1(
    const float* __restrict__ AT, const float* __restrict__ W,
    float* __restrict__ part)
{
    __shared__ f4 As[2][16][16];
    __shared__ f4 Ws[2][16][64];
    int t = threadIdx.x;
    int n0 = blockIdx.x << 8;
    int by = blockIdx.y;
    size_t kbase = (size_t)by * 576;

    int mi2 = (t & 7) * 2;
    int nj2 = (t >> 3) * 2;
    int wr = t >> 6, wc = t & 63;

    f4 acc[8][2];
#pragma unroll
    for (int mm = 0; mm < 8; ++mm) { acc[mm][0] = (f4)0.f; acc[mm][1] = (f4)0.f; }

    const f4* gA = (const f4*)(AT + kbase * 64);
    const float* Wb = W + kbase * 1024 + n0;

    {
        f4 pa = gA[t];
        const float* Wc = Wb + (size_t)wr * 1024 + wc * 4;
        f4 pw0 = *(const f4*)(Wc);
        f4 pw1 = *(const f4*)(Wc + 4096);
        f4 pw2 = *(const f4*)(Wc + 8192);
        f4 pw3 = *(const f4*)(Wc + 12288);
        As[0][t >> 4][t & 15] = pa;
        Ws[0][wr][wc] = pw0;
        Ws[0][wr + 4][wc] = pw1;
        Ws[0][wr + 8][wc] = pw2;
        Ws[0][wr + 12][wc] = pw3;
    }
    __syncthreads();

    int cur = 0;
#pragma unroll 1
    for (int cc = 0; cc < 36; ++cc) {
        f4 pa, pw0, pw1, pw2, pw3;
        if (cc < 35) {
            pa = gA[(cc + 1) * 256 + t];
            const float* Wc = Wb + (size_t)((cc + 1) * 16 + wr) * 1024 + wc * 4;
            pw0 = *(const f4*)(Wc);
            pw1 = *(const f4*)(Wc + 4096);
            pw2 = *(const f4*)(Wc + 8192);
            pw3 = *(const f4*)(Wc + 12288);
        }
#pragma unroll 4
        for (int k = 0; k < 16; ++k) {
            f4 a0 = As[cur][k][mi2], a1 = As[cur][k][mi2 + 1];
            f4 w0 = Ws[cur][k][nj2], w1 = Ws[cur][k][nj2 + 1];
            acc[0][0] += w0 * a0.x;  acc[0][1] += w1 * a0.x;
            acc[1][0] += w0 * a0.y;  acc[1][1] += w1 * a0.y;
            acc[2][0] += w0 * a0.z;  acc[2][1] += w1 * a0.z;
            acc[3][0] += w0 * a0.w;  acc[3][1] += w1 * a0.w;
            acc[4][0] += w0 * a1.x;  acc[4][1] += w1 * a1.x;
            acc[5][0] += w0 * a1.y;  acc[5][1] += w1 * a1.y;
            acc[6][0] += w0 * a1.z;  acc[6][1] += w1 * a1.z;
            acc[7][0] += w0 * a1.w;  acc[7][1] += w1 * a1.w;
        }
        if (cc < 35) {
            int nb = cur ^ 1;
            As[nb][t >> 4][t & 15] = pa;
            Ws[nb][wr][wc] = pw0;
            Ws[nb][wr + 4][wc] = pw1;
            Ws[nb][wr + 8][wc] = pw2;
            Ws[nb][wr + 12][wc] = pw3;
        }
        __syncthreads();
        cur ^= 1;
    }

    float* pb = part + (size_t)by * 65536 + n0 + nj2 * 4;
#pragma unroll
    for (int mm = 0; mm < 8; ++mm) {
        float* row = pb + (size_t)(mi2 * 4 + mm) * 1024;
        *(f4*)(row)     = acc[mm][0];
        *(f4*)(row + 4) = acc[mm][1];
    }
}

// ===========================================================================
// Generic skinny GEMM (fc2): AT[k][64] uniform (s_load), W[k][n] coalesced.
// ===========================================================================
__global__ __launch_bounds__(256) void k_gemm(
    const float* __restrict__ AT, const float* __restrict__ W,
    float* __restrict__ part, int K, int N, int KC)
{
    int n = blockIdx.x * 256 + threadIdx.x;
    int kc = blockIdx.y;
    int k0 = kc * KC;
    int k1 = k0 + KC; if (k1 > K) k1 = K;
    float acc[64];
#pragma unroll
    for (int m = 0; m < 64; ++m) acc[m] = 0.f;
#pragma unroll 2
    for (int k = k0; k < k1; ++k) {
        float wv = W[(size_t)k * N + n];
        const float4* Ak4 = (const float4*)(AT + (size_t)k * 64);
#pragma unroll
        for (int mq = 0; mq < 16; ++mq) {
            float4 a = Ak4[mq];
            acc[4 * mq + 0] = fmaf(a.x, wv, acc[4 * mq + 0]);
            acc[4 * mq + 1] = fmaf(a.y, wv, acc[4 * mq + 1]);
            acc[4 * mq + 2] = fmaf(a.z, wv, acc[4 * mq + 2]);
            acc[4 * mq + 3] = fmaf(a.w, wv, acc[4 * mq + 3]);
        }
    }
    float4* p4 = (float4*)(part + ((size_t)kc * N + n) * 64);
#pragma unroll
    for (int mq = 0; mq < 16; ++mq)
        p4[mq] = make_float4(acc[4 * mq], acc[4 * mq + 1], acc[4 * mq + 2], acc[4 * mq + 3]);
}

// ===========================================================================
// fc1 reduce: part[by][m][n] (by=0..249) -> pp[s][m][n] (s=0..9, 25 each)
// ===========================================================================
__global__ __launch_bounds__(256) void k_redA(
    const float* __restrict__ part, float* __restrict__ pp)
{
    int id = blockIdx.x * 256 + threadIdx.x;  // 163840
    int r = id & 16383; int s = id >> 14;
    const f4* p = (const f4*)part;
    f4 v = (f4)0.f;
#pragma unroll 5
    for (int c = s * 25; c < s * 25 + 25; ++c)
        v += p[(size_t)c * 16384 + r];
    ((f4*)pp)[(size_t)s * 16384 + r] = v;
}

// pp[s][m][n] -> h1T[n][m] (+bias, relu).
__global__ __launch_bounds__(256) void k_redB(
    const float* __restrict__ pp, const float* __restrict__ bias,
    float* __restrict__ h1T)
{
    int id = blockIdx.x * 256 + threadIdx.x;  // 16384
    int m = id >> 8, nq = id & 255;
    const f4* p = (const f4*)pp;
    f4 s = (f4)0.f;
#pragma unroll
    for (int c = 0; c < 10; ++c) s += p[(size_t)c * 16384 + m * 256 + nq];
    f4 bv = ((const f4*)bias)[nq];
    s += bv;
    s.x = frelu(s.x); s.y = frelu(s.y); s.z = frelu(s.z); s.w = frelu(s.w);
    int n = nq * 4;
    h1T[(size_t)(n + 0) * 64 + m] = s.x;
    h1T[(size_t)(n + 1) * 64 + m] = s.y;
    h1T[(size_t)(n + 2) * 64 + m] = s.z;
    h1T[(size_t)(n + 3) * 64 + m] = s.w;
}

// Reduce fc2 partials; write M-MAJOR out[m][n].
__global__ __launch_bounds__(256) void k_red(
    const float* __restrict__ part, const float* __restrict__ bias,
    float* __restrict__ outM, int N, int C)
{
    int id = blockIdx.x * 256 + threadIdx.x;  // N*16
    int mq = id & 15, n = id >> 4;
    f4 s = (f4)0.f;
    for (int c = 0; c < C; ++c)
        s += *(const f4*)(part + ((size_t)c * N + n) * 64 + mq * 4);
    float bv = bias[n];
    s += bv;
    outM[(size_t)(mq * 4 + 0) * N + n] = s.x;
    outM[(size_t)(mq * 4 + 1) * N + n] = s.y;
    outM[(size_t)(mq * 4 + 2) * N + n] = s.z;
    outM[(size_t)(mq * 4 + 3) * N + n] = s.w;
}

// ===========================================================================
// fc3: block = one m row; h2M[m][k] wave-uniform (s_load broadcast).
// ===========================================================================
__global__ __launch_bounds__(192) void k_fc3(
    const float* __restrict__ h2M, const float* __restrict__ w3,
    const float* __restrict__ b3, float* __restrict__ out)
{
    int m = blockIdx.x;                      // 64
    int o = threadIdx.x;                     // 192, active < 150
    int oc = o < 150 ? o : 149;
    const float* hr = h2M + (size_t)m * 1024;
    float s = b3[oc];
#pragma unroll 8
    for (int k = 0; k < 1024; ++k) s = fmaf(hr[k], w3[k * 150 + oc], s);
    if (o < 150) out[m * 150 + o] = s;
}

// ---------------------------------------------------------------------------
extern "C" void kernel_launch(void* const* d_in, const int* in_sizes, int n_in,
                              void* d_out, int out_size, void* d_ws, size_t ws_size,
                              hipStream_t stream) {
    const float* X    = (const float*)d_in[0];
    const float* c1w1 = (const float*)d_in[1];
    const float* c1b1 = (const float*)d_in[2];
    const float* c1w2 = (const float*)d_in[3];
    const float* c1b2 = (const float*)d_in[4];
    const float* a1W  = (const float*)d_in[5];
    const float* a1b  = (const float*)d_in[6];
    const float* c2w1 = (const float*)d_in[7];
    const float* c2b1 = (const float*)d_in[8];
    const float* c2w2 = (const float*)d_in[9];
    const float* c2b2 = (const float*)d_in[10];
    const float* a2W  = (const float*)d_in[11];
    const float* a2b  = (const float*)d_in[12];
    const float* c3w1 = (const float*)d_in[13];
    const float* c3b1 = (const float*)d_in[14];
    const float* c3w2 = (const float*)d_in[15];
    const float* c3b2 = (const float*)d_in[16];
    const float* a3W  = (const float*)d_in[17];
    const float* a3b  = (const float*)d_in[18];
    const float* fc1w = (const float*)d_in[19];
    const float* fc1b = (const float*)d_in[20];
    const float* fc2w = (const float*)d_in[21];
    const float* fc2b = (const float*)d_in[22];
    const float* fc3w = (const float*)d_in[23];
    const float* fc3b = (const float*)d_in[24];

    float* ws  = (float*)d_ws;
    float* x1p = ws;                       // [0, 10.24M)
    float* x2p = ws + 10240000;            // [10.24M, 14.336M)
    float* x3p = ws + 14336000;            // [14.336M, 16.384M)
    float* e1  = ws + 16384000;            // [16.384M, 17.984M)
    float* e2  = ws + 17984000;
    float* e3  = ws + 18304000;
    float* z   = ws + 18368000;            // [18.368M, 25.536M)  dead after k_zt
    float* zT  = ws + 25536000;            // [25.536M, 34.752M)  live through k_gemm1
    float* p1  = ws;                       // 250*65536 = 16.384M exactly
    float* pp  = ws + 16384000;            // 163,840  (old e1, dead)
    float* h1T = ws + 16600000;            // 65,536
    float* p2  = ws + 16700000;            // 64*1024*64 = 4.19M (ends 20.9M)
    float* h2M = ws + 21000000;            // 65,536

    k_s1<<<3200, 128, 0, stream>>>(X, c1w1, c1b1, c1w2, c1b2, a1W, a1b, x1p, e1);
    k_t1<<<3200, 64, 0, stream>>>(e1, X, c1w1, c1b1, c1w2, c1b2, z);
    k_s2<<<640, 128, 0, stream>>>(x1p, c2w1, c2b1, c2w2, c2b2, a2W, a2b, x2p, e2);
    k_t2<<<3200, 64, 0, stream>>>(e2, x1p, c2w1, c2b1, c2w2, c2b2, z);
    k_s3<<<1000, 256, 0, stream>>>(x2p, c3w1, c3b1, c3w2, c3b2, a3W, a3b, x3p, e3);
    k_t3<<<3200, 64, 0, stream>>>(e3, x2p, c3w1, c3b1, c3w2, c3b2, z);
    k_zt<<<1750, 256, 0, stream>>>(z, zT);
    k_xf<<<250, 256, 0, stream>>>(x3p, zT);

    k_gemm1<<<dim3(4, 250), 256, 0, stream>>>(zT, fc1w, p1);
    k_redA<<<640, 256, 0, stream>>>(p1, pp);
    k_redB<<<64, 256, 0, stream>>>(pp, fc1b, h1T);
    k_gemm<<<dim3(4, 64), 256, 0, stream>>>(h1T, fc2w, p2, 1024, 1024, 16);
    k_red<<<64, 256, 0, stream>>>(p2, fc2b, h2M, 1024, 64);
    k_fc3<<<64, 192, 0, stream>>>(h2M, fc3w, fc3b, (float*)d_out);
}

// Round 9
// 1121.537 us; speedup vs baseline: 1.3189x; 1.3189x over previous
//
#include <hip/hip_runtime.h>
#include <math.h>

#define DEV __device__ __forceinline__
DEV float frelu(float x) { return x > 0.f ? x : 0.f; }

typedef float f4 __attribute__((ext_vector_type(4)));

// ===========================================================================
// Stage 1 (WREG, R7 form + tanh dropped): conv 3->32 relu -> conv 32->32 relu
// e1 = raw attention score (tanh monotone, only ordering used); pool5 -> x1p.
// lane = out channel (32 per half-wave); per-lane weights in VGPRs, batched
// over NG1 pool groups to amortize the preload.
// ===========================================================================
#define NG1 8
__global__ __launch_bounds__(256) void k_s1(
    const float* __restrict__ x,
    const float* __restrict__ w1, const float* __restrict__ b1,
    const float* __restrict__ w2, const float* __restrict__ b2,
    const float* __restrict__ aW, const float* __restrict__ ab,
    float* __restrict__ x1p, float* __restrict__ e1)
{
    __shared__ float v1s[4][2][32];
    int tid = threadIdx.x;
    int wv = tid >> 6, lane = tid & 63;
    int half = lane >> 5, o = lane & 31;
    int hs = blockIdx.x * 8 + wv * 2 + half;     // 40000 half-slots

    float W1c0 = w1[o], W1c1 = w1[32 + o], W1c2 = w1[64 + o], B1 = b1[o];
    float W2[32];
#pragma unroll
    for (int i = 0; i < 32; ++i) W2[i] = w2[i * 32 + o];
    float B2 = b2[o];
    float* vs = &v1s[wv][half][0];

#pragma unroll 1
    for (int i = 0; i < NG1; ++i) {
        int g = hs * NG1 + i;                    // 0..319999
        int b = g / 5000, r = g % 5000, h = r / 100, pw = r % 100;
        float AWo = aW[h * 32 + o];
        const float* xrow = x + (size_t)((b * 50 + h) * 500) * 3;
        float vmax = 0.f;
#pragma unroll 1
        for (int j = 0; j < 5; ++j) {
            int w = pw * 5 + j;
            float x0 = xrow[w * 3 + 0], x1v = xrow[w * 3 + 1], x2v = xrow[w * 3 + 2];
            float v1 = frelu(fmaf(x0, W1c0, fmaf(x1v, W1c1, fmaf(x2v, W1c2, B1))));
            vs[o] = v1;
            float a2 = B2;
#pragma unroll
            for (int q = 0; q < 32; q += 4) {
                float4 v4 = *(const float4*)&vs[q];
                a2 = fmaf(v4.x, W2[q + 0], a2);
                a2 = fmaf(v4.y, W2[q + 1], a2);
                a2 = fmaf(v4.z, W2[q + 2], a2);
                a2 = fmaf(v4.w, W2[q + 3], a2);
            }
            float t = frelu(a2);
            vmax = fmaxf(vmax, t);
            float ep = t * AWo;
            ep += __shfl_xor(ep, 1, 64);
            ep += __shfl_xor(ep, 2, 64);
            ep += __shfl_xor(ep, 4, 64);
            ep += __shfl_xor(ep, 8, 64);
            ep += __shfl_xor(ep, 16, 64);
            if (o == 0) e1[(b * 50 + h) * 500 + w] = ep + ab[h * 500 + w];  // raw
        }
        x1p[(size_t)g * 32 + o] = vmax;
    }
}

// ===========================================================================
// Stage 2 (WREG, R7 form + tanh dropped): conv 32->64 relu -> conv 64->64
// relu ; e2 raw ; pool5 -> x2p. lane = out channel (64), NG2=16.
// ===========================================================================
#define NG2 16
__global__ __launch_bounds__(256) void k_s2(
    const float* __restrict__ x1p,
    const float* __restrict__ w1, const float* __restrict__ b1,
    const float* __restrict__ w2, const float* __restrict__ b2,
    const float* __restrict__ aW, const float* __restrict__ ab,
    float* __restrict__ x2p, float* __restrict__ e2)
{
    __shared__ float v1s[4][64];
    int tid = threadIdx.x;
    int wv = tid >> 6, o = tid & 63;
    int slot = blockIdx.x * 4 + wv;              // 4000 slots

    float W1[32];
#pragma unroll
    for (int i = 0; i < 32; ++i) W1[i] = w1[i * 64 + o];
    float W2[64];
#pragma unroll
    for (int i = 0; i < 64; ++i) W2[i] = w2[i * 64 + o];
    float B1 = b1[o], B2 = b2[o];
    float* vs = &v1s[wv][0];

#pragma unroll 1
    for (int i = 0; i < NG2; ++i) {
        int g = slot * NG2 + i;                  // 0..63999
        int b = g / 1000, r = g % 1000, h = r / 20, pw = r % 20;
        float AWo = aW[h * 64 + o];
        float vmax = 0.f;
#pragma unroll 1
        for (int j = 0; j < 5; ++j) {
            int w = pw * 5 + j;
            const float* in = x1p + (size_t)((b * 50 + h) * 100 + w) * 32;
            float a1 = B1;
#pragma unroll
            for (int q = 0; q < 32; q += 4) {
                float4 a4 = *(const float4*)&in[q];
                a1 = fmaf(a4.x, W1[q + 0], a1);
                a1 = fmaf(a4.y, W1[q + 1], a1);
                a1 = fmaf(a4.z, W1[q + 2], a1);
                a1 = fmaf(a4.w, W1[q + 3], a1);
            }
            vs[o] = frelu(a1);
            float a2 = B2;
#pragma unroll
            for (int q = 0; q < 64; q += 4) {
                float4 v4 = *(const float4*)&vs[q];
                a2 = fmaf(v4.x, W2[q + 0], a2);
                a2 = fmaf(v4.y, W2[q + 1], a2);
                a2 = fmaf(v4.z, W2[q + 2], a2);
                a2 = fmaf(v4.w, W2[q + 3], a2);
            }
            float t = frelu(a2);
            vmax = fmaxf(vmax, t);
            float ep = t * AWo;
            ep += __shfl_xor(ep, 1, 64);
            ep += __shfl_xor(ep, 2, 64);
            ep += __shfl_xor(ep, 4, 64);
            ep += __shfl_xor(ep, 8, 64);
            ep += __shfl_xor(ep, 16, 64);
            ep += __shfl_xor(ep, 32, 64);
            if (o == 0) e2[(b * 50 + h) * 100 + w] = ep + ab[h * 100 + w];  // raw
        }
        x2p[(size_t)g * 64 + o] = vmax;
    }
}

// ===========================================================================
// Stage 3 (WREG, split accumulators): conv 64->128 relu -> conv 128->128 relu
// e3 raw ; pool4 -> x3p. NG3=8, grid 1000.
// ===========================================================================
#define NG3 8
__global__ __launch_bounds__(256) void k_s3(
    const float* __restrict__ x2p,
    const float* __restrict__ w1, const float* __restrict__ b1,
    const float* __restrict__ w2, const float* __restrict__ b2,
    const float* __restrict__ aW, const float* __restrict__ ab,
    float* __restrict__ x3p, float* __restrict__ e3)
{
    __shared__ float v1s[2][128];
    __shared__ float epart[2][2];
    int tid = threadIdx.x;
    int wv = tid >> 6, lane = tid & 63;
    int slot = wv >> 1, oh = wv & 1;
    int o = oh * 64 + lane;
    int gs = blockIdx.x * 2 + slot;              // 2000 slots

    float W1[64];
#pragma unroll
    for (int i = 0; i < 64; ++i) W1[i] = w1[i * 128 + o];
    float W2[128];
#pragma unroll
    for (int i = 0; i < 128; ++i) W2[i] = w2[i * 128 + o];
    float B1 = b1[o], B2 = b2[o];

#pragma unroll 1
    for (int i = 0; i < NG3; ++i) {
        int g = gs * NG3 + i;                    // 0..15999
        int b = g / 250, r = g % 250, h = r / 5, pw = r % 5;
        float AWo = aW[h * 128 + o];
        float vmax = 0.f;
#pragma unroll 1
        for (int j = 0; j < 4; ++j) {
            int w = pw * 4 + j;
            const float* in = x2p + (size_t)((b * 50 + h) * 20 + w) * 64;
            float a1a = B1, a1b = 0.f;
#pragma unroll
            for (int q = 0; q < 64; q += 8) {
                float4 a4 = *(const float4*)&in[q];
                float4 b4 = *(const float4*)&in[q + 4];
                a1a = fmaf(a4.x, W1[q + 0], a1a);
                a1b = fmaf(a4.y, W1[q + 1], a1b);
                a1a = fmaf(a4.z, W1[q + 2], a1a);
                a1b = fmaf(a4.w, W1[q + 3], a1b);
                a1a = fmaf(b4.x, W1[q + 4], a1a);
                a1b = fmaf(b4.y, W1[q + 5], a1b);
                a1a = fmaf(b4.z, W1[q + 6], a1a);
                a1b = fmaf(b4.w, W1[q + 7], a1b);
            }
            v1s[slot][o] = frelu(a1a + a1b);
            __syncthreads();
            float a2a = B2, a2b = 0.f, a2c = 0.f, a2d = 0.f;
#pragma unroll
            for (int q = 0; q < 128; q += 8) {
                float4 a4 = *(const float4*)&v1s[slot][q];
                float4 b4 = *(const float4*)&v1s[slot][q + 4];
                a2a = fmaf(a4.x, W2[q + 0], a2a);
                a2b = fmaf(a4.y, W2[q + 1], a2b);
                a2c = fmaf(a4.z, W2[q + 2], a2c);
                a2d = fmaf(a4.w, W2[q + 3], a2d);
                a2a = fmaf(b4.x, W2[q + 4], a2a);
                a2b = fmaf(b4.y, W2[q + 5], a2b);
                a2c = fmaf(b4.z, W2[q + 6], a2c);
                a2d = fmaf(b4.w, W2[q + 7], a2d);
            }
            float t = frelu((a2a + a2b) + (a2c + a2d));
            vmax = fmaxf(vmax, t);
            float ep = t * AWo;
            ep += __shfl_xor(ep, 1, 64);
            ep += __shfl_xor(ep, 2, 64);
            ep += __shfl_xor(ep, 4, 64);
            ep += __shfl_xor(ep, 8, 64);
            ep += __shfl_xor(ep, 16, 64);
            ep += __shfl_xor(ep, 32, 64);
            if (lane == 0) epart[slot][oh] = ep;
            __syncthreads();
            if (lane == 0 && oh == 0)
                e3[(b * 50 + h) * 20 + w] = epart[slot][0] + epart[slot][1] + ab[h * 20 + w];
        }
        x3p[(size_t)g * 128 + o] = vmax;
    }
}

// ===========================================================================
// Top-k (k=10, value desc, tie -> lower index) + feature recompute.
// ===========================================================================
__global__ __launch_bounds__(64) void k_t1(
    const float* __restrict__ e1, const float* __restrict__ x,
    const float* __restrict__ w1, const float* __restrict__ b1,
    const float* __restrict__ w2, const float* __restrict__ b2,
    float* __restrict__ z)
{
    int blk = blockIdx.x; int b = blk / 50; int h = blk % 50;
    int lane = threadIdx.x;
    const float* er = e1 + (b * 50 + h) * 500;
    float ev0 = er[lane];
    float ev1 = er[64 + lane];
    float ev2 = er[128 + lane];
    float ev3 = er[192 + lane];
    float ev4 = er[256 + lane];
    float ev5 = er[320 + lane];
    float ev6 = er[384 + lane];
    float ev7 = (448 + lane < 500) ? er[448 + lane] : -1e30f;

    for (int k = 0; k < 10; ++k) {
        float bv = ev0; int bi = lane;
        if (ev1 > bv) { bv = ev1; bi = 64 + lane; }
        if (ev2 > bv) { bv = ev2; bi = 128 + lane; }
        if (ev3 > bv) { bv = ev3; bi = 192 + lane; }
        if (ev4 > bv) { bv = ev4; bi = 256 + lane; }
        if (ev5 > bv) { bv = ev5; bi = 320 + lane; }
        if (ev6 > bv) { bv = ev6; bi = 384 + lane; }
        if (ev7 > bv) { bv = ev7; bi = 448 + lane; }
#pragma unroll
        for (int d = 1; d < 64; d <<= 1) {
            float ov = __shfl_xor(bv, d, 64); int oi = __shfl_xor(bi, d, 64);
            if (ov > bv || (ov == bv && oi < bi)) { bv = ov; bi = oi; }
        }
        bool me = (bi & 63) == lane; int cs = bi >> 6;
        if (me && cs == 0) ev0 = -1e30f;
        if (me && cs == 1) ev1 = -1e30f;
        if (me && cs == 2) ev2 = -1e30f;
        if (me && cs == 3) ev3 = -1e30f;
        if (me && cs == 4) ev4 = -1e30f;
        if (me && cs == 5) ev5 = -1e30f;
        if (me && cs == 6) ev6 = -1e30f;
        if (me && cs == 7) ev7 = -1e30f;

        const float* px = x + (size_t)((b * 50 + h) * 500 + bi) * 3;
        float x0 = px[0], x1v = px[1], x2v = px[2];
        int o = lane & 31;
        float v1 = frelu(fmaf(x0, w1[o], fmaf(x1v, w1[32 + o], fmaf(x2v, w1[64 + o], b1[o]))));
        float v2 = b2[o];
#pragma unroll 8
        for (int i = 0; i < 32; ++i) v2 = fmaf(__shfl(v1, i, 64), w2[i * 32 + o], v2);
        if (lane < 32) z[(size_t)b * 112000 + h * 320 + k * 32 + o] = frelu(v2);
    }
}

__global__ __launch_bounds__(64) void k_t2(
    const float* __restrict__ e2, const float* __restrict__ x1p,
    const float* __restrict__ w1, const float* __restrict__ b1,
    const float* __restrict__ w2, const float* __restrict__ b2,
    float* __restrict__ z)
{
    int blk = blockIdx.x; int b = blk / 50; int h = blk % 50;
    int lane = threadIdx.x;
    const float* er = e2 + (b * 50 + h) * 100;
    float ev0 = er[lane];
    float ev1 = (64 + lane < 100) ? er[64 + lane] : -1e30f;

    for (int k = 0; k < 10; ++k) {
        float bv = ev0; int bi = lane;
        if (ev1 > bv) { bv = ev1; bi = 64 + lane; }
#pragma unroll
        for (int d = 1; d < 64; d <<= 1) {
            float ov = __shfl_xor(bv, d, 64); int oi = __shfl_xor(bi, d, 64);
            if (ov > bv || (ov == bv && oi < bi)) { bv = ov; bi = oi; }
        }
        bool me = (bi & 63) == lane; int cs = bi >> 6;
        if (me && cs == 0) ev0 = -1e30f;
        if (me && cs == 1) ev1 = -1e30f;

        const float* in = x1p + (size_t)((b * 50 + h) * 100 + bi) * 32;
        float v1p0 = b1[lane], v1p1 = 0.f;
#pragma unroll 8
        for (int i = 0; i < 32; i += 2) {
            v1p0 = fmaf(in[i], w1[i * 64 + lane], v1p0);
            v1p1 = fmaf(in[i + 1], w1[(i + 1) * 64 + lane], v1p1);
        }
        float v1 = frelu(v1p0 + v1p1);
        float v2p0 = b2[lane], v2p1 = 0.f;
#pragma unroll 8
        for (int i = 0; i < 64; i += 2) {
            v2p0 = fmaf(__shfl(v1, i, 64), w2[i * 64 + lane], v2p0);
            v2p1 = fmaf(__shfl(v1, i + 1, 64), w2[(i + 1) * 64 + lane], v2p1);
        }
        z[(size_t)b * 112000 + 16000 + h * 640 + k * 64 + lane] = frelu(v2p0 + v2p1);
    }
}

__global__ __launch_bounds__(64) void k_t3(
    const float* __restrict__ e3, const float* __restrict__ x2p,
    const float* __restrict__ w1, const float* __restrict__ b1,
    const float* __restrict__ w2, const float* __restrict__ b2,
    float* __restrict__ z)
{
    int blk = blockIdx.x; int b = blk / 50; int h = blk % 50;
    int lane = threadIdx.x;
    const float* er = e3 + (b * 50 + h) * 20;
    float ev0 = (lane < 20) ? er[lane] : -1e30f;

    for (int k = 0; k < 10; ++k) {
        float bv = ev0; int bi = lane;
#pragma unroll
        for (int d = 1; d < 64; d <<= 1) {
            float ov = __shfl_xor(bv, d, 64); int oi = __shfl_xor(bi, d, 64);
            if (ov > bv || (ov == bv && oi < bi)) { bv = ov; bi = oi; }
        }
        if (bi == lane) ev0 = -1e30f;
        const float* in = x2p + (size_t)((b * 50 + h) * 20 + bi) * 64;
        float v1a0 = b1[lane], v1a1 = 0.f, v1b0 = b1[lane + 64], v1b1 = 0.f;
#pragma unroll 8
        for (int i = 0; i < 64; i += 2) {
            float a0 = in[i], a1 = in[i + 1];
            v1a0 = fmaf(a0, w1[i * 128 + lane], v1a0);
            v1b0 = fmaf(a0, w1[i * 128 + lane + 64], v1b0);
            v1a1 = fmaf(a1, w1[(i + 1) * 128 + lane], v1a1);
            v1b1 = fmaf(a1, w1[(i + 1) * 128 + lane + 64], v1b1);
        }
        float v1a = frelu(v1a0 + v1a1), v1b = frelu(v1b0 + v1b1);
        float v2a0 = b2[lane], v2a1 = 0.f, v2b0 = b2[lane + 64], v2b1 = 0.f;
#pragma unroll 8
        for (int i = 0; i < 64; i += 2) {
            float s0 = __shfl(v1a, i, 64), s1 = __shfl(v1a, i + 1, 64);
            v2a0 = fmaf(s0, w2[i * 128 + lane], v2a0);
            v2b0 = fmaf(s0, w2[i * 128 + lane + 64], v2b0);
            v2a1 = fmaf(s1, w2[(i + 1) * 128 + lane], v2a1);
            v2b1 = fmaf(s1, w2[(i + 1) * 128 + lane + 64], v2b1);
        }
#pragma unroll 8
        for (int i = 0; i < 64; i += 2) {
            float s0 = __shfl(v1b, i, 64), s1 = __shfl(v1b, i + 1, 64);
            v2a0 = fmaf(s0, w2[(i + 64) * 128 + lane], v2a0);
            v2b0 = fmaf(s0, w2[(i + 64) * 128 + lane + 64], v2b0);
            v2a1 = fmaf(s1, w2[(i + 65) * 128 + lane], v2a1);
            v2b1 = fmaf(s1, w2[(i + 65) * 128 + lane + 64], v2b1);
        }
        size_t base = (size_t)b * 112000 + 48000 + h * 1280 + k * 128;
        z[base + lane] = frelu(v2a0 + v2a1);
        z[base + lane + 64] = frelu(v2b0 + v2b1);
    }
}

// ===========================================================================
// k_zt: transpose z[m][f] (f<112000) -> zT[f][m]
// ===========================================================================
__global__ __launch_bounds__(256) void k_zt(const float* __restrict__ z, float* __restrict__ zT)
{
    __shared__ float t[64][65];
    int f0 = blockIdx.x * 64;                // 1750 blocks
    int tid = threadIdx.x;
    int fl = tid & 63, q = tid >> 6;
#pragma unroll
    for (int rr = 0; rr < 16; ++rr) {
        int m = q * 16 + rr;
        t[m][fl] = z[(size_t)m * 112000 + f0 + fl];
    }
    __syncthreads();
    int m2 = tid & 63;
#pragma unroll
    for (int rr = 0; rr < 16; ++rr) {
        int fl2 = q * 16 + rr;
        zT[(size_t)(f0 + fl2) * 64 + m2] = t[m2][fl2];
    }
}

// ===========================================================================
// k_xf: x3p (B,H,5,128) -> zT rows 112000 + c*250 + h*5 + pw, layout [f][m]
// ===========================================================================
__global__ __launch_bounds__(256) void k_xf(const float* __restrict__ x3p, float* __restrict__ zT)
{
    __shared__ float t[64][129];
    int blk = blockIdx.x;                    // 250
    int h = blk / 5, pw = blk % 5;
    int tid = threadIdx.x;
    for (int idx = tid; idx < 64 * 128; idx += 256) {
        int m = idx >> 7, c = idx & 127;
        t[m][c] = x3p[(size_t)((m * 50 + h) * 5 + pw) * 128 + c];
    }
    __syncthreads();
    for (int idx = tid; idx < 64 * 128; idx += 256) {
        int c = idx >> 6, m = idx & 63;
        zT[(size_t)(112000 + c * 250 + h * 5 + pw) * 64 + m] = t[m][c];
    }
}

// ===========================================================================
// fc1 GEMM — double-buffered LDS tile (R7, proven <345 us).
// Block tile 64m x 256n, BK=16, thread tile 8m x 8n, grid (4, 250).
// ===========================================================================
__global__ __launch_bounds__(256, 4) void k_gemm1(
    const float* __restrict__ AT, const float* __restrict__ W,
    float* __restrict__ part)
{
    __shared__ f4 As[2][16][16];
    __shared__ f4 Ws[2][16][64];
    int t = threadIdx.x;
    int n0 = blockIdx.x << 8;
    int by = blockIdx.y;
    size_t kbase = (size_t)by * 576;

    int mi2 = (t & 7) * 2;
    int nj2 = (t >> 3) * 2;
    int wr = t >> 6, wc = t & 63;

    f4 acc[8][2];
#pragma unroll
    for (int mm = 0; mm < 8; ++mm) { acc[mm][0] = (f4)0.f; acc[mm][1] = (f4)0.f; }

    const f4* gA = (const f4*)(AT + kbase * 64);
    const float* Wb = W + kbase * 1024 + n0;

    {
        f4 pa = gA[t];
        const float* Wc = Wb + (size_t)wr * 1024 + wc * 4;
        f4 pw0 = *(const f4*)(Wc);
        f4 pw1 = *(const f4*)(Wc + 4096);
        f4 pw2 = *(const f4*)(Wc + 8192);
        f4 pw3 = *(const f4*)(Wc + 12288);
        As[0][t >> 4][t & 15] = pa;
        Ws[0][wr][wc] = pw0;
        Ws[0][wr + 4][wc] = pw1;
        Ws[0][wr + 8][wc] = pw2;
        Ws[0][wr + 12][wc] = pw3;
    }
    __syncthreads();

    int cur = 0;
#pragma unroll 1
    for (int cc = 0; cc < 36; ++cc) {
        f4 pa, pw0, pw1, pw2, pw3;
        if (cc < 35) {
            pa = gA[(cc + 1) * 256 + t];
            const float* Wc = Wb + (size_t)((cc + 1) * 16 + wr) * 1024 + wc * 4;
            pw0 = *(const f4*)(Wc);
            pw1 = *(const f4*)(Wc + 4096);
            pw2 = *(const f4*)(Wc + 8192);
            pw3 = *(const f4*)(Wc + 12288);
        }
#pragma unroll 4
        for (int k = 0; k < 16; ++k) {
            f4 a0 = As[cur][k][mi2], a1 = As[cur][k][mi2 + 1];
            f4 w0 = Ws[cur][k][nj2], w1 = Ws[cur][k][nj2 + 1];
            acc[0][0] += w0 * a0.x;  acc[0][1] += w1 * a0.x;
            acc[1][0] += w0 * a0.y;  acc[1][1] += w1 * a0.y;
            acc[2][0] += w0 * a0.z;  acc[2][1] += w1 * a0.z;
            acc[3][0] += w0 * a0.w;  acc[3][1] += w1 * a0.w;
            acc[4][0] += w0 * a1.x;  acc[4][1] += w1 * a1.x;
            acc[5][0] += w0 * a1.y;  acc[5][1] += w1 * a1.y;
            acc[6][0] += w0 * a1.z;  acc[6][1] += w1 * a1.z;
            acc[7][0] += w0 * a1.w;  acc[7][1] += w1 * a1.w;
        }
        if (cc < 35) {
            int nb = cur ^ 1;
            As[nb][t >> 4][t & 15] = pa;
            Ws[nb][wr][wc] = pw0;
            Ws[nb][wr + 4][wc] = pw1;
            Ws[nb][wr + 8][wc] = pw2;
            Ws[nb][wr + 12][wc] = pw3;
        }
        __syncthreads();
        cur ^= 1;
    }

    float* pb = part + (size_t)by * 65536 + n0 + nj2 * 4;
#pragma unroll
    for (int mm = 0; mm < 8; ++mm) {
        float* row = pb + (size_t)(mi2 * 4 + mm) * 1024;
        *(f4*)(row)     = acc[mm][0];
        *(f4*)(row + 4) = acc[mm][1];
    }
}

// ===========================================================================
// Generic skinny GEMM (fc2): AT[k][64] uniform (s_load), W[k][n] coalesced.
// ===========================================================================
__global__ __launch_bounds__(256) void k_gemm(
    const float* __restrict__ AT, const float* __restrict__ W,
    float* __restrict__ part, int K, int N, int KC)
{
    int n = blockIdx.x * 256 + threadIdx.x;
    int kc = blockIdx.y;
    int k0 = kc * KC;
    int k1 = k0 + KC; if (k1 > K) k1 = K;
    float acc[64];
#pragma unroll
    for (int m = 0; m < 64; ++m) acc[m] = 0.f;
#pragma unroll 2
    for (int k = k0; k < k1; ++k) {
        float wv = W[(size_t)k * N + n];
        const float4* Ak4 = (const float4*)(AT + (size_t)k * 64);
#pragma unroll
        for (int mq = 0; mq < 16; ++mq) {
            float4 a = Ak4[mq];
            acc[4 * mq + 0] = fmaf(a.x, wv, acc[4 * mq + 0]);
            acc[4 * mq + 1] = fmaf(a.y, wv, acc[4 * mq + 1]);
            acc[4 * mq + 2] = fmaf(a.z, wv, acc[4 * mq + 2]);
            acc[4 * mq + 3] = fmaf(a.w, wv, acc[4 * mq + 3]);
        }
    }
    float4* p4 = (float4*)(part + ((size_t)kc * N + n) * 64);
#pragma unroll
    for (int mq = 0; mq < 16; ++mq)
        p4[mq] = make_float4(acc[4 * mq], acc[4 * mq + 1], acc[4 * mq + 2], acc[4 * mq + 3]);
}

// ===========================================================================
// fc1 reduce: part[by][m][n] (by=0..249) -> pp[s][m][n] (s=0..9, 25 each)
// ===========================================================================
__global__ __launch_bounds__(256) void k_redA(
    const float* __restrict__ part, float* __restrict__ pp)
{
    int id = blockIdx.x * 256 + threadIdx.x;  // 163840
    int r = id & 16383; int s = id >> 14;
    const f4* p = (const f4*)part;
    f4 v = (f4)0.f;
#pragma unroll 5
    for (int c = s * 25; c < s * 25 + 25; ++c)
        v += p[(size_t)c * 16384 + r];
    ((f4*)pp)[(size_t)s * 16384 + r] = v;
}

// pp[s][m][n] -> h1T[n][m] (+bias, relu).
__global__ __launch_bounds__(256) void k_redB(
    const float* __restrict__ pp, const float* __restrict__ bias,
    float* __restrict__ h1T)
{
    int id = blockIdx.x * 256 + threadIdx.x;  // 16384
    int m = id >> 8, nq = id & 255;
    const f4* p = (const f4*)pp;
    f4 s = (f4)0.f;
#pragma unroll
    for (int c = 0; c < 10; ++c) s += p[(size_t)c * 16384 + m * 256 + nq];
    f4 bv = ((const f4*)bias)[nq];
    s += bv;
    s.x = frelu(s.x); s.y = frelu(s.y); s.z = frelu(s.z); s.w = frelu(s.w);
    int n = nq * 4;
    h1T[(size_t)(n + 0) * 64 + m] = s.x;
    h1T[(size_t)(n + 1) * 64 + m] = s.y;
    h1T[(size_t)(n + 2) * 64 + m] = s.z;
    h1T[(size_t)(n + 3) * 64 + m] = s.w;
}

// Reduce fc2 partials; write M-MAJOR out[m][n].
__global__ __launch_bounds__(256) void k_red(
    const float* __restrict__ part, const float* __restrict__ bias,
    float* __restrict__ outM, int N, int C)
{
    int id = blockIdx.x * 256 + threadIdx.x;  // N*16
    int mq = id & 15, n = id >> 4;
    f4 s = (f4)0.f;
    for (int c = 0; c < C; ++c)
        s += *(const f4*)(part + ((size_t)c * N + n) * 64 + mq * 4);
    float bv = bias[n];
    s += bv;
    outM[(size_t)(mq * 4 + 0) * N + n] = s.x;
    outM[(size_t)(mq * 4 + 1) * N + n] = s.y;
    outM[(size_t)(mq * 4 + 2) * N + n] = s.z;
    outM[(size_t)(mq * 4 + 3) * N + n] = s.w;
}

// ===========================================================================
// fc3: block = one m row; h2M[m][k] wave-uniform (s_load broadcast).
// ===========================================================================
__global__ __launch_bounds__(192) void k_fc3(
    const float* __restrict__ h2M, const float* __restrict__ w3,
    const float* __restrict__ b3, float* __restrict__ out)
{
    int m = blockIdx.x;                      // 64
    int o = threadIdx.x;                     // 192, active < 150
    int oc = o < 150 ? o : 149;
    const float* hr = h2M + (size_t)m * 1024;
    float s = b3[oc];
#pragma unroll 8
    for (int k = 0; k < 1024; ++k) s = fmaf(hr[k], w3[k * 150 + oc], s);
    if (o < 150) out[m * 150 + o] = s;
}

// ---------------------------------------------------------------------------
extern "C" void kernel_launch(void* const* d_in, const int* in_sizes, int n_in,
                              void* d_out, int out_size, void* d_ws, size_t ws_size,
                              hipStream_t stream) {
    const float* X    = (const float*)d_in[0];
    const float* c1w1 = (const float*)d_in[1];
    const float* c1b1 = (const float*)d_in[2];
    const float* c1w2 = (const float*)d_in[3];
    const float* c1b2 = (const float*)d_in[4];
    const float* a1W  = (const float*)d_in[5];
    const float* a1b  = (const float*)d_in[6];
    const float* c2w1 = (const float*)d_in[7];
    const float* c2b1 = (const float*)d_in[8];
    const float* c2w2 = (const float*)d_in[9];
    const float* c2b2 = (const float*)d_in[10];
    const float* a2W  = (const float*)d_in[11];
    const float* a2b  = (const float*)d_in[12];
    const float* c3w1 = (const float*)d_in[13];
    const float* c3b1 = (const float*)d_in[14];
    const float* c3w2 = (const float*)d_in[15];
    const float* c3b2 = (const float*)d_in[16];
    const float* a3W  = (const float*)d_in[17];
    const float* a3b  = (const float*)d_in[18];
    const float* fc1w = (const float*)d_in[19];
    const float* fc1b = (const float*)d_in[20];
    const float* fc2w = (const float*)d_in[21];
    const float* fc2b = (const float*)d_in[22];
    const float* fc3w = (const float*)d_in[23];
    const float* fc3b = (const float*)d_in[24];

    float* ws  = (float*)d_ws;
    float* x1p = ws;                       // [0, 10.24M)
    float* x2p = ws + 10240000;            // [10.24M, 14.336M)
    float* x3p = ws + 14336000;            // [14.336M, 16.384M)
    float* e1  = ws + 16384000;            // [16.384M, 17.984M)
    float* e2  = ws + 17984000;
    float* e3  = ws + 18304000;
    float* z   = ws + 18368000;            // [18.368M, 25.536M)  dead after k_zt
    float* zT  = ws + 25536000;            // [25.536M, 34.752M)  live through k_gemm1
    float* p1  = ws;                       // 250*65536 = 16.384M exactly
    float* pp  = ws + 16384000;            // 163,840  (old e1, dead)
    float* h1T = ws + 16600000;            // 65,536
    float* p2  = ws + 16700000;            // 64*1024*64 = 4.19M (ends 20.9M)
    float* h2M = ws + 21000000;            // 65,536

    k_s1<<<5000, 256, 0, stream>>>(X, c1w1, c1b1, c1w2, c1b2, a1W, a1b, x1p, e1);
    k_t1<<<3200, 64, 0, stream>>>(e1, X, c1w1, c1b1, c1w2, c1b2, z);
    k_s2<<<1000, 256, 0, stream>>>(x1p, c2w1, c2b1, c2w2, c2b2, a2W, a2b, x2p, e2);
    k_t2<<<3200, 64, 0, stream>>>(e2, x1p, c2w1, c2b1, c2w2, c2b2, z);
    k_s3<<<1000, 256, 0, stream>>>(x2p, c3w1, c3b1, c3w2, c3b2, a3W, a3b, x3p, e3);
    k_t3<<<3200, 64, 0, stream>>>(e3, x2p, c3w1, c3b1, c3w2, c3b2, z);
    k_zt<<<1750, 256, 0, stream>>>(z, zT);
    k_xf<<<250, 256, 0, stream>>>(x3p, zT);

    k_gemm1<<<dim3(4, 250), 256, 0, stream>>>(zT, fc1w, p1);
    k_redA<<<640, 256, 0, stream>>>(p1, pp);
    k_redB<<<64, 256, 0, stream>>>(pp, fc1b, h1T);
    k_gemm<<<dim3(4, 64), 256, 0, stream>>>(h1T, fc2w, p2, 1024, 1024, 16);
    k_red<<<64, 256, 0, stream>>>(p2, fc2b, h2M, 1024, 64);
    k_fc3<<<64, 192, 0, stream>>>(h2M, fc3w, fc3b, (float*)d_out);
}

// Round 10
// 975.635 us; speedup vs baseline: 1.5161x; 1.1495x over previous
//
#include <hip/hip_runtime.h>
#include <math.h>

#define DEV __device__ __forceinline__
DEV float frelu(float x) { return x > 0.f ? x : 0.f; }

typedef float f4 __attribute__((ext_vector_type(4)));
typedef short bf16x8 __attribute__((ext_vector_type(8)));
typedef int   i2x  __attribute__((ext_vector_type(2)));

DEV unsigned pack_hi2(float a, float b) {
    return (__float_as_uint(b) & 0xFFFF0000u) | (__float_as_uint(a) >> 16);
}
DEV float hi_part(float a) {
    return __uint_as_float(__float_as_uint(a) & 0xFFFF0000u);
}

// ===========================================================================
// Stage 1 (WREG): conv 3->32 relu -> conv 32->32 relu ; e1 raw ; pool5 -> x1p
// ===========================================================================
#define NG1 8
__global__ __launch_bounds__(256) void k_s1(
    const float* __restrict__ x,
    const float* __restrict__ w1, const float* __restrict__ b1,
    const float* __restrict__ w2, const float* __restrict__ b2,
    const float* __restrict__ aW, const float* __restrict__ ab,
    float* __restrict__ x1p, float* __restrict__ e1)
{
    __shared__ float v1s[4][2][32];
    int tid = threadIdx.x;
    int wv = tid >> 6, lane = tid & 63;
    int half = lane >> 5, o = lane & 31;
    int hs = blockIdx.x * 8 + wv * 2 + half;     // 40000 half-slots

    float W1c0 = w1[o], W1c1 = w1[32 + o], W1c2 = w1[64 + o], B1 = b1[o];
    float W2[32];
#pragma unroll
    for (int i = 0; i < 32; ++i) W2[i] = w2[i * 32 + o];
    float B2 = b2[o];
    float* vs = &v1s[wv][half][0];

#pragma unroll 1
    for (int i = 0; i < NG1; ++i) {
        int g = hs * NG1 + i;                    // 0..319999
        int b = g / 5000, r = g % 5000, h = r / 100, pw = r % 100;
        float AWo = aW[h * 32 + o];
        const float* xrow = x + (size_t)((b * 50 + h) * 500) * 3;
        float vmax = 0.f;
#pragma unroll 1
        for (int j = 0; j < 5; ++j) {
            int w = pw * 5 + j;
            float x0 = xrow[w * 3 + 0], x1v = xrow[w * 3 + 1], x2v = xrow[w * 3 + 2];
            float v1 = frelu(fmaf(x0, W1c0, fmaf(x1v, W1c1, fmaf(x2v, W1c2, B1))));
            vs[o] = v1;
            float a2 = B2;
#pragma unroll
            for (int q = 0; q < 32; q += 4) {
                float4 v4 = *(const float4*)&vs[q];
                a2 = fmaf(v4.x, W2[q + 0], a2);
                a2 = fmaf(v4.y, W2[q + 1], a2);
                a2 = fmaf(v4.z, W2[q + 2], a2);
                a2 = fmaf(v4.w, W2[q + 3], a2);
            }
            float t = frelu(a2);
            vmax = fmaxf(vmax, t);
            float ep = t * AWo;
            ep += __shfl_xor(ep, 1, 64);
            ep += __shfl_xor(ep, 2, 64);
            ep += __shfl_xor(ep, 4, 64);
            ep += __shfl_xor(ep, 8, 64);
            ep += __shfl_xor(ep, 16, 64);
            if (o == 0) e1[(b * 50 + h) * 500 + w] = ep + ab[h * 500 + w];
        }
        x1p[(size_t)g * 32 + o] = vmax;
    }
}

// ===========================================================================
// Stage 2 (WREG): conv 32->64 relu -> conv 64->64 relu ; e2 raw ; pool5
// ===========================================================================
#define NG2 16
__global__ __launch_bounds__(256) void k_s2(
    const float* __restrict__ x1p,
    const float* __restrict__ w1, const float* __restrict__ b1,
    const float* __restrict__ w2, const float* __restrict__ b2,
    const float* __restrict__ aW, const float* __restrict__ ab,
    float* __restrict__ x2p, float* __restrict__ e2)
{
    __shared__ float v1s[4][64];
    int tid = threadIdx.x;
    int wv = tid >> 6, o = tid & 63;
    int slot = blockIdx.x * 4 + wv;              // 4000 slots

    float W1[32];
#pragma unroll
    for (int i = 0; i < 32; ++i) W1[i] = w1[i * 64 + o];
    float W2[64];
#pragma unroll
    for (int i = 0; i < 64; ++i) W2[i] = w2[i * 64 + o];
    float B1 = b1[o], B2 = b2[o];
    float* vs = &v1s[wv][0];

#pragma unroll 1
    for (int i = 0; i < NG2; ++i) {
        int g = slot * NG2 + i;                  // 0..63999
        int b = g / 1000, r = g % 1000, h = r / 20, pw = r % 20;
        float AWo = aW[h * 64 + o];
        float vmax = 0.f;
#pragma unroll 1
        for (int j = 0; j < 5; ++j) {
            int w = pw * 5 + j;
            const float* in = x1p + (size_t)((b * 50 + h) * 100 + w) * 32;
            float a1 = B1;
#pragma unroll
            for (int q = 0; q < 32; q += 4) {
                float4 a4 = *(const float4*)&in[q];
                a1 = fmaf(a4.x, W1[q + 0], a1);
                a1 = fmaf(a4.y, W1[q + 1], a1);
                a1 = fmaf(a4.z, W1[q + 2], a1);
                a1 = fmaf(a4.w, W1[q + 3], a1);
            }
            vs[o] = frelu(a1);
            float a2 = B2;
#pragma unroll
            for (int q = 0; q < 64; q += 4) {
                float4 v4 = *(const float4*)&vs[q];
                a2 = fmaf(v4.x, W2[q + 0], a2);
                a2 = fmaf(v4.y, W2[q + 1], a2);
                a2 = fmaf(v4.z, W2[q + 2], a2);
                a2 = fmaf(v4.w, W2[q + 3], a2);
            }
            float t = frelu(a2);
            vmax = fmaxf(vmax, t);
            float ep = t * AWo;
            ep += __shfl_xor(ep, 1, 64);
            ep += __shfl_xor(ep, 2, 64);
            ep += __shfl_xor(ep, 4, 64);
            ep += __shfl_xor(ep, 8, 64);
            ep += __shfl_xor(ep, 16, 64);
            ep += __shfl_xor(ep, 32, 64);
            if (o == 0) e2[(b * 50 + h) * 100 + w] = ep + ab[h * 100 + w];
        }
        x2p[(size_t)g * 64 + o] = vmax;
    }
}

// ===========================================================================
// Stage 3 (WREG, split accumulators): conv 64->128 -> conv 128->128 ; e3 raw
// ===========================================================================
#define NG3 8
__global__ __launch_bounds__(256) void k_s3(
    const float* __restrict__ x2p,
    const float* __restrict__ w1, const float* __restrict__ b1,
    const float* __restrict__ w2, const float* __restrict__ b2,
    const float* __restrict__ aW, const float* __restrict__ ab,
    float* __restrict__ x3p, float* __restrict__ e3)
{
    __shared__ float v1s[2][128];
    __shared__ float epart[2][2];
    int tid = threadIdx.x;
    int wv = tid >> 6, lane = tid & 63;
    int slot = wv >> 1, oh = wv & 1;
    int o = oh * 64 + lane;
    int gs = blockIdx.x * 2 + slot;              // 2000 slots

    float W1[64];
#pragma unroll
    for (int i = 0; i < 64; ++i) W1[i] = w1[i * 128 + o];
    float W2[128];
#pragma unroll
    for (int i = 0; i < 128; ++i) W2[i] = w2[i * 128 + o];
    float B1 = b1[o], B2 = b2[o];

#pragma unroll 1
    for (int i = 0; i < NG3; ++i) {
        int g = gs * NG3 + i;                    // 0..15999
        int b = g / 250, r = g % 250, h = r / 5, pw = r % 5;
        float AWo = aW[h * 128 + o];
        float vmax = 0.f;
#pragma unroll 1
        for (int j = 0; j < 4; ++j) {
            int w = pw * 4 + j;
            const float* in = x2p + (size_t)((b * 50 + h) * 20 + w) * 64;
            float a1a = B1, a1b = 0.f;
#pragma unroll
            for (int q = 0; q < 64; q += 8) {
                float4 a4 = *(const float4*)&in[q];
                float4 b4 = *(const float4*)&in[q + 4];
                a1a = fmaf(a4.x, W1[q + 0], a1a);
                a1b = fmaf(a4.y, W1[q + 1], a1b);
                a1a = fmaf(a4.z, W1[q + 2], a1a);
                a1b = fmaf(a4.w, W1[q + 3], a1b);
                a1a = fmaf(b4.x, W1[q + 4], a1a);
                a1b = fmaf(b4.y, W1[q + 5], a1b);
                a1a = fmaf(b4.z, W1[q + 6], a1a);
                a1b = fmaf(b4.w, W1[q + 7], a1b);
            }
            v1s[slot][o] = frelu(a1a + a1b);
            __syncthreads();
            float a2a = B2, a2b = 0.f, a2c = 0.f, a2d = 0.f;
#pragma unroll
            for (int q = 0; q < 128; q += 8) {
                float4 a4 = *(const float4*)&v1s[slot][q];
                float4 b4 = *(const float4*)&v1s[slot][q + 4];
                a2a = fmaf(a4.x, W2[q + 0], a2a);
                a2b = fmaf(a4.y, W2[q + 1], a2b);
                a2c = fmaf(a4.z, W2[q + 2], a2c);
                a2d = fmaf(a4.w, W2[q + 3], a2d);
                a2a = fmaf(b4.x, W2[q + 4], a2a);
                a2b = fmaf(b4.y, W2[q + 5], a2b);
                a2c = fmaf(b4.z, W2[q + 6], a2c);
                a2d = fmaf(b4.w, W2[q + 7], a2d);
            }
            float t = frelu((a2a + a2b) + (a2c + a2d));
            vmax = fmaxf(vmax, t);
            float ep = t * AWo;
            ep += __shfl_xor(ep, 1, 64);
            ep += __shfl_xor(ep, 2, 64);
            ep += __shfl_xor(ep, 4, 64);
            ep += __shfl_xor(ep, 8, 64);
            ep += __shfl_xor(ep, 16, 64);
            ep += __shfl_xor(ep, 32, 64);
            if (lane == 0) epart[slot][oh] = ep;
            __syncthreads();
            if (lane == 0 && oh == 0)
                e3[(b * 50 + h) * 20 + w] = epart[slot][0] + epart[slot][1] + ab[h * 20 + w];
        }
        x3p[(size_t)g * 128 + o] = vmax;
    }
}

// ===========================================================================
// Top-k (k=10, value desc, tie -> lower index) + feature recompute.
// ===========================================================================
__global__ __launch_bounds__(64) void k_t1(
    const float* __restrict__ e1, const float* __restrict__ x,
    const float* __restrict__ w1, const float* __restrict__ b1,
    const float* __restrict__ w2, const float* __restrict__ b2,
    float* __restrict__ z)
{
    int blk = blockIdx.x; int b = blk / 50; int h = blk % 50;
    int lane = threadIdx.x;
    const float* er = e1 + (b * 50 + h) * 500;
    float ev0 = er[lane];
    float ev1 = er[64 + lane];
    float ev2 = er[128 + lane];
    float ev3 = er[192 + lane];
    float ev4 = er[256 + lane];
    float ev5 = er[320 + lane];
    float ev6 = er[384 + lane];
    float ev7 = (448 + lane < 500) ? er[448 + lane] : -1e30f;

    for (int k = 0; k < 10; ++k) {
        float bv = ev0; int bi = lane;
        if (ev1 > bv) { bv = ev1; bi = 64 + lane; }
        if (ev2 > bv) { bv = ev2; bi = 128 + lane; }
        if (ev3 > bv) { bv = ev3; bi = 192 + lane; }
        if (ev4 > bv) { bv = ev4; bi = 256 + lane; }
        if (ev5 > bv) { bv = ev5; bi = 320 + lane; }
        if (ev6 > bv) { bv = ev6; bi = 384 + lane; }
        if (ev7 > bv) { bv = ev7; bi = 448 + lane; }
#pragma unroll
        for (int d = 1; d < 64; d <<= 1) {
            float ov = __shfl_xor(bv, d, 64); int oi = __shfl_xor(bi, d, 64);
            if (ov > bv || (ov == bv && oi < bi)) { bv = ov; bi = oi; }
        }
        bool me = (bi & 63) == lane; int cs = bi >> 6;
        if (me && cs == 0) ev0 = -1e30f;
        if (me && cs == 1) ev1 = -1e30f;
        if (me && cs == 2) ev2 = -1e30f;
        if (me && cs == 3) ev3 = -1e30f;
        if (me && cs == 4) ev4 = -1e30f;
        if (me && cs == 5) ev5 = -1e30f;
        if (me && cs == 6) ev6 = -1e30f;
        if (me && cs == 7) ev7 = -1e30f;

        const float* px = x + (size_t)((b * 50 + h) * 500 + bi) * 3;
        float x0 = px[0], x1v = px[1], x2v = px[2];
        int o = lane & 31;
        float v1 = frelu(fmaf(x0, w1[o], fmaf(x1v, w1[32 + o], fmaf(x2v, w1[64 + o], b1[o]))));
        float v2 = b2[o];
#pragma unroll 8
        for (int i = 0; i < 32; ++i) v2 = fmaf(__shfl(v1, i, 64), w2[i * 32 + o], v2);
        if (lane < 32) z[(size_t)b * 112000 + h * 320 + k * 32 + o] = frelu(v2);
    }
}

__global__ __launch_bounds__(64) void k_t2(
    const float* __restrict__ e2, const float* __restrict__ x1p,
    const float* __restrict__ w1, const float* __restrict__ b1,
    const float* __restrict__ w2, const float* __restrict__ b2,
    float* __restrict__ z)
{
    int blk = blockIdx.x; int b = blk / 50; int h = blk % 50;
    int lane = threadIdx.x;
    const float* er = e2 + (b * 50 + h) * 100;
    float ev0 = er[lane];
    float ev1 = (64 + lane < 100) ? er[64 + lane] : -1e30f;

    for (int k = 0; k < 10; ++k) {
        float bv = ev0; int bi = lane;
        if (ev1 > bv) { bv = ev1; bi = 64 + lane; }
#pragma unroll
        for (int d = 1; d < 64; d <<= 1) {
            float ov = __shfl_xor(bv, d, 64); int oi = __shfl_xor(bi, d, 64);
            if (ov > bv || (ov == bv && oi < bi)) { bv = ov; bi = oi; }
        }
        bool me = (bi & 63) == lane; int cs = bi >> 6;
        if (me && cs == 0) ev0 = -1e30f;
        if (me && cs == 1) ev1 = -1e30f;

        const float* in = x1p + (size_t)((b * 50 + h) * 100 + bi) * 32;
        float v1p0 = b1[lane], v1p1 = 0.f;
#pragma unroll 8
        for (int i = 0; i < 32; i += 2) {
            v1p0 = fmaf(in[i], w1[i * 64 + lane], v1p0);
            v1p1 = fmaf(in[i + 1], w1[(i + 1) * 64 + lane], v1p1);
        }
        float v1 = frelu(v1p0 + v1p1);
        float v2p0 = b2[lane], v2p1 = 0.f;
#pragma unroll 8
        for (int i = 0; i < 64; i += 2) {
            v2p0 = fmaf(__shfl(v1, i, 64), w2[i * 64 + lane], v2p0);
            v2p1 = fmaf(__shfl(v1, i + 1, 64), w2[(i + 1) * 64 + lane], v2p1);
        }
        z[(size_t)b * 112000 + 16000 + h * 640 + k * 64 + lane] = frelu(v2p0 + v2p1);
    }
}

__global__ __launch_bounds__(64) void k_t3(
    const float* __restrict__ e3, const float* __restrict__ x2p,
    const float* __restrict__ w1, const float* __restrict__ b1,
    const float* __restrict__ w2, const float* __restrict__ b2,
    float* __restrict__ z)
{
    int blk = blockIdx.x; int b = blk / 50; int h = blk % 50;
    int lane = threadIdx.x;
    const float* er = e3 + (b * 50 + h) * 20;
    float ev0 = (lane < 20) ? er[lane] : -1e30f;

    for (int k = 0; k < 10; ++k) {
        float bv = ev0; int bi = lane;
#pragma unroll
        for (int d = 1; d < 64; d <<= 1) {
            float ov = __shfl_xor(bv, d, 64); int oi = __shfl_xor(bi, d, 64);
            if (ov > bv || (ov == bv && oi < bi)) { bv = ov; bi = oi; }
        }
        if (bi == lane) ev0 = -1e30f;
        const float* in = x2p + (size_t)((b * 50 + h) * 20 + bi) * 64;
        float v1a0 = b1[lane], v1a1 = 0.f, v1b0 = b1[lane + 64], v1b1 = 0.f;
#pragma unroll 8
        for (int i = 0; i < 64; i += 2) {
            float a0 = in[i], a1 = in[i + 1];
            v1a0 = fmaf(a0, w1[i * 128 + lane], v1a0);
            v1b0 = fmaf(a0, w1[i * 128 + lane + 64], v1b0);
            v1a1 = fmaf(a1, w1[(i + 1) * 128 + lane], v1a1);
            v1b1 = fmaf(a1, w1[(i + 1) * 128 + lane + 64], v1b1);
        }
        float v1a = frelu(v1a0 + v1a1), v1b = frelu(v1b0 + v1b1);
        float v2a0 = b2[lane], v2a1 = 0.f, v2b0 = b2[lane + 64], v2b1 = 0.f;
#pragma unroll 8
        for (int i = 0; i < 64; i += 2) {
            float s0 = __shfl(v1a, i, 64), s1 = __shfl(v1a, i + 1, 64);
            v2a0 = fmaf(s0, w2[i * 128 + lane], v2a0);
            v2b0 = fmaf(s0, w2[i * 128 + lane + 64], v2b0);
            v2a1 = fmaf(s1, w2[(i + 1) * 128 + lane], v2a1);
            v2b1 = fmaf(s1, w2[(i + 1) * 128 + lane + 64], v2b1);
        }
#pragma unroll 8
        for (int i = 0; i < 64; i += 2) {
            float s0 = __shfl(v1b, i, 64), s1 = __shfl(v1b, i + 1, 64);
            v2a0 = fmaf(s0, w2[(i + 64) * 128 + lane], v2a0);
            v2b0 = fmaf(s0, w2[(i + 64) * 128 + lane + 64], v2b0);
            v2a1 = fmaf(s1, w2[(i + 65) * 128 + lane], v2a1);
            v2b1 = fmaf(s1, w2[(i + 65) * 128 + lane + 64], v2b1);
        }
        size_t base = (size_t)b * 112000 + 48000 + h * 1280 + k * 128;
        z[base + lane] = frelu(v2a0 + v2a1);
        z[base + lane + 64] = frelu(v2b0 + v2b1);
    }
}

// ===========================================================================
// k_zt: transpose z[m][f] (f<112000) -> zT[f][m]
// ===========================================================================
__global__ __launch_bounds__(256) void k_zt(const float* __restrict__ z, float* __restrict__ zT)
{
    __shared__ float t[64][65];
    int f0 = blockIdx.x * 64;                // 1750 blocks
    int tid = threadIdx.x;
    int fl = tid & 63, q = tid >> 6;
#pragma unroll
    for (int rr = 0; rr < 16; ++rr) {
        int m = q * 16 + rr;
        t[m][fl] = z[(size_t)m * 112000 + f0 + fl];
    }
    __syncthreads();
    int m2 = tid & 63;
#pragma unroll
    for (int rr = 0; rr < 16; ++rr) {
        int fl2 = q * 16 + rr;
        zT[(size_t)(f0 + fl2) * 64 + m2] = t[m2][fl2];
    }
}

// ===========================================================================
// k_xf: x3p (B,H,5,128) -> zT rows 112000 + c*250 + h*5 + pw, layout [f][m]
// ===========================================================================
__global__ __launch_bounds__(256) void k_xf(const float* __restrict__ x3p, float* __restrict__ zT)
{
    __shared__ float t[64][129];
    int blk = blockIdx.x;                    // 250
    int h = blk / 5, pw = blk % 5;
    int tid = threadIdx.x;
    for (int idx = tid; idx < 64 * 128; idx += 256) {
        int m = idx >> 7, c = idx & 127;
        t[m][c] = x3p[(size_t)((m * 50 + h) * 5 + pw) * 128 + c];
    }
    __syncthreads();
    for (int idx = tid; idx < 64 * 128; idx += 256) {
        int c = idx >> 6, m = idx & 63;
        zT[(size_t)(112000 + c * 250 + h * 5 + pw) * 64 + m] = t[m][c];
    }
}

// ===========================================================================
// fc1 GEMM — bf16-split MFMA (16x16x32), part[n][m] = sum W[k][n]*zT[k][m].
// Key invariant: A-frag (W) and B-frag (zT) are built with the IDENTICAL
// lane->k bijection f(hi,j)=hi*8+j (one ds_read_b128 per frag), so the MFMA
// k-sum is correct for ANY hardware k-permutation. C/D layout is the
// HW-verified col=lane&15, row=(lane>>4)*4+reg.
// Split: x = hi + lo (bf16 trunc); D += Whi*Ahi + Whi*Alo + Wlo*Ahi.
// Block: n-tile 128 (wave w -> nf {2w,2w+1}), m = 64, K-chunk 1152 (36x32).
// LDS (single buffer, 24.5 KB): WH[128][32]bf16 @0, WL @8192,
//   AH[64][32] @16384, AL @20480; 16B k-chunks XOR-swizzled by (n&3)/(m&3).
// grid (8, 125) = 1000 blocks.
// ===========================================================================
__global__ __launch_bounds__(256, 3) void k_gemm1(
    const float* __restrict__ AT, const float* __restrict__ W,
    float* __restrict__ part)
{
    __shared__ char smem[24576];
    const int t = threadIdx.x;
    const int lane = t & 63;
    const int wv = t >> 6;
    const int n0 = blockIdx.x << 7;          // 8 n-blocks * 128
    const int kc = blockIdx.y;               // 125 k-chunks * 1152

    // ---- staging decode (thread-constant) ----
    const int nw = t & 127, kqi = t >> 7;    // W: thread covers 16 k at col nw
    const int ma = t & 63,  kqa = t >> 6;    // A: thread covers 8 k at col ma

    int wadrW[4];
#pragma unroll
    for (int q = 0; q < 4; ++q)
        wadrW[q] = nw * 64 + (((kqi * 2 + (q >> 1)) ^ (nw & 3)) << 4) + ((q & 1) << 3);
    int wadrA[2];
#pragma unroll
    for (int q = 0; q < 2; ++q)
        wadrA[q] = 16384 + ma * 64 + ((kqa ^ (ma & 3)) << 4) + (q << 3);

    // ---- frag read addresses (thread-constant) ----
    const int c = lane & 15, hi = lane >> 4;
    int rW[2], rA[4];
#pragma unroll
    for (int i = 0; i < 2; ++i) {
        int nl = (2 * wv + i) * 16 + c;
        rW[i] = nl * 64 + ((hi ^ (c & 3)) << 4);
    }
#pragma unroll
    for (int mf = 0; mf < 4; ++mf) {
        int ml = mf * 16 + c;
        rA[mf] = 16384 + ml * 64 + ((hi ^ (c & 3)) << 4);
    }

    f4 acc[2][4];
#pragma unroll
    for (int i = 0; i < 2; ++i)
#pragma unroll
        for (int mf = 0; mf < 4; ++mf) acc[i][mf] = (f4)0.f;

    const float* Wp = W + ((size_t)kc * 1152 + kqi * 16) * 1024 + (n0 + nw);
    const float* Ap = AT + ((size_t)kc * 1152 + kqa * 8) * 64 + ma;

    float gw[16], ga[8];
#pragma unroll
    for (int j = 0; j < 16; ++j) gw[j] = Wp[(size_t)j * 1024];
#pragma unroll
    for (int j = 0; j < 8; ++j) ga[j] = Ap[j * 64];
    Wp += 32768; Ap += 2048;

#pragma unroll 1
    for (int cc = 0; cc < 36; ++cc) {
        // convert current tile (trunc split)
        i2x whv[4], wlv[4], ahv[2], alv[2];
#pragma unroll
        for (int q = 0; q < 4; ++q) {
            float x0 = gw[q * 4 + 0], x1 = gw[q * 4 + 1];
            float x2 = gw[q * 4 + 2], x3 = gw[q * 4 + 3];
            whv[q].x = pack_hi2(x0, x1); whv[q].y = pack_hi2(x2, x3);
            float l0 = x0 - hi_part(x0), l1 = x1 - hi_part(x1);
            float l2 = x2 - hi_part(x2), l3 = x3 - hi_part(x3);
            wlv[q].x = pack_hi2(l0, l1); wlv[q].y = pack_hi2(l2, l3);
        }
#pragma unroll
        for (int q = 0; q < 2; ++q) {
            float x0 = ga[q * 4 + 0], x1 = ga[q * 4 + 1];
            float x2 = ga[q * 4 + 2], x3 = ga[q * 4 + 3];
            ahv[q].x = pack_hi2(x0, x1); ahv[q].y = pack_hi2(x2, x3);
            float l0 = x0 - hi_part(x0), l1 = x1 - hi_part(x1);
            float l2 = x2 - hi_part(x2), l3 = x3 - hi_part(x3);
            alv[q].x = pack_hi2(l0, l1); alv[q].y = pack_hi2(l2, l3);
        }
        __syncthreads();           // prior step's frag reads complete
#pragma unroll
        for (int q = 0; q < 4; ++q) {
            *(i2x*)(smem + wadrW[q]) = whv[q];
            *(i2x*)(smem + wadrW[q] + 8192) = wlv[q];
        }
#pragma unroll
        for (int q = 0; q < 2; ++q) {
            *(i2x*)(smem + wadrA[q]) = ahv[q];
            *(i2x*)(smem + wadrA[q] + 4096) = alv[q];
        }
        if (cc < 35) {             // issue next tile loads (in flight over MFMA)
#pragma unroll
            for (int j = 0; j < 16; ++j) gw[j] = Wp[(size_t)j * 1024];
#pragma unroll
            for (int j = 0; j < 8; ++j) ga[j] = Ap[j * 64];
            Wp += 32768; Ap += 2048;
        }
        __syncthreads();           // publish LDS tile

        bf16x8 fwh[2], fwl[2], fah[4], fal[4];
#pragma unroll
        for (int i = 0; i < 2; ++i) {
            fwh[i] = *(const bf16x8*)(smem + rW[i]);
            fwl[i] = *(const bf16x8*)(smem + rW[i] + 8192);
        }
#pragma unroll
        for (int mf = 0; mf < 4; ++mf) {
            fah[mf] = *(const bf16x8*)(smem + rA[mf]);
            fal[mf] = *(const bf16x8*)(smem + rA[mf] + 4096);
        }
#pragma unroll
        for (int i = 0; i < 2; ++i)
#pragma unroll
            for (int mf = 0; mf < 4; ++mf) {
                acc[i][mf] = __builtin_amdgcn_mfma_f32_16x16x32_bf16(fwh[i], fah[mf], acc[i][mf], 0, 0, 0);
                acc[i][mf] = __builtin_amdgcn_mfma_f32_16x16x32_bf16(fwh[i], fal[mf], acc[i][mf], 0, 0, 0);
                acc[i][mf] = __builtin_amdgcn_mfma_f32_16x16x32_bf16(fwl[i], fah[mf], acc[i][mf], 0, 0, 0);
            }
    }

    // epilogue: part[kc][n][m]; D: col(m16)=lane&15, row(n16)=(lane>>4)*4+q
    float* pb = part + ((size_t)kc * 1024 + n0) * 64;
#pragma unroll
    for (int i = 0; i < 2; ++i) {
        int nf = 2 * wv + i;
#pragma unroll
        for (int mf = 0; mf < 4; ++mf) {
#pragma unroll
            for (int q = 0; q < 4; ++q) {
                int n = nf * 16 + hi * 4 + q;
                int m = mf * 16 + c;
                pb[(size_t)n * 64 + m] = acc[i][mf][q];
            }
        }
    }
}

// ===========================================================================
// Generic skinny GEMM (fc2): AT[k][64] uniform (s_load), W[k][n] coalesced.
// ===========================================================================
__global__ __launch_bounds__(256) void k_gemm(
    const float* __restrict__ AT, const float* __restrict__ W,
    float* __restrict__ part, int K, int N, int KC)
{
    int n = blockIdx.x * 256 + threadIdx.x;
    int kc = blockIdx.y;
    int k0 = kc * KC;
    int k1 = k0 + KC; if (k1 > K) k1 = K;
    float acc[64];
#pragma unroll
    for (int m = 0; m < 64; ++m) acc[m] = 0.f;
#pragma unroll 2
    for (int k = k0; k < k1; ++k) {
        float wv = W[(size_t)k * N + n];
        const float4* Ak4 = (const float4*)(AT + (size_t)k * 64);
#pragma unroll
        for (int mq = 0; mq < 16; ++mq) {
            float4 a = Ak4[mq];
            acc[4 * mq + 0] = fmaf(a.x, wv, acc[4 * mq + 0]);
            acc[4 * mq + 1] = fmaf(a.y, wv, acc[4 * mq + 1]);
            acc[4 * mq + 2] = fmaf(a.z, wv, acc[4 * mq + 2]);
            acc[4 * mq + 3] = fmaf(a.w, wv, acc[4 * mq + 3]);
        }
    }
    float4* p4 = (float4*)(part + ((size_t)kc * N + n) * 64);
#pragma unroll
    for (int mq = 0; mq < 16; ++mq)
        p4[mq] = make_float4(acc[4 * mq], acc[4 * mq + 1], acc[4 * mq + 2], acc[4 * mq + 3]);
}

// ===========================================================================
// fc1 reduce: part[kc][n][m] (kc=0..124) -> pp[s][n][m] (s=0..4, 25 each)
// ===========================================================================
__global__ __launch_bounds__(256) void k_redA(
    const float* __restrict__ part, float* __restrict__ pp)
{
    int id = blockIdx.x * 256 + threadIdx.x;  // 81920
    int r = id & 16383; int s = id >> 14;     // s in [0,5)
    const f4* p = (const f4*)part;
    f4 v = (f4)0.f;
#pragma unroll 5
    for (int cidx = s * 25; cidx < s * 25 + 25; ++cidx)
        v += p[(size_t)cidx * 16384 + r];
    ((f4*)pp)[(size_t)s * 16384 + r] = v;
}

// pp[s][n][m] -> h1T[n][m] (+bias, relu). (part layout is already [n][m].)
__global__ __launch_bounds__(256) void k_redB(
    const float* __restrict__ pp, const float* __restrict__ bias,
    float* __restrict__ h1T)
{
    int id = blockIdx.x * 256 + threadIdx.x;  // 16384
    int mq = id & 15, n = id >> 4;
    const f4* p = (const f4*)pp;
    f4 s = (f4)0.f;
#pragma unroll
    for (int cidx = 0; cidx < 5; ++cidx) s += p[(size_t)cidx * 16384 + id];
    float bv = bias[n];
    s += bv;
    s.x = frelu(s.x); s.y = frelu(s.y); s.z = frelu(s.z); s.w = frelu(s.w);
    *(f4*)(h1T + (size_t)n * 64 + mq * 4) = s;
}

// Reduce fc2 partials; write M-MAJOR out[m][n].
__global__ __launch_bounds__(256) void k_red(
    const float* __restrict__ part, const float* __restrict__ bias,
    float* __restrict__ outM, int N, int C)
{
    int id = blockIdx.x * 256 + threadIdx.x;  // N*16
    int mq = id & 15, n = id >> 4;
    f4 s = (f4)0.f;
    for (int cidx = 0; cidx < C; ++cidx)
        s += *(const f4*)(part + ((size_t)cidx * N + n) * 64 + mq * 4);
    float bv = bias[n];
    s += bv;
    outM[(size_t)(mq * 4 + 0) * N + n] = s.x;
    outM[(size_t)(mq * 4 + 1) * N + n] = s.y;
    outM[(size_t)(mq * 4 + 2) * N + n] = s.z;
    outM[(size_t)(mq * 4 + 3) * N + n] = s.w;
}

// ===========================================================================
// fc3: block = one m row; h2M[m][k] wave-uniform (s_load broadcast).
// ===========================================================================
__global__ __launch_bounds__(192) void k_fc3(
    const float* __restrict__ h2M, const float* __restrict__ w3,
    const float* __restrict__ b3, float* __restrict__ out)
{
    int m = blockIdx.x;                      // 64
    int o = threadIdx.x;                     // 192, active < 150
    int oc = o < 150 ? o : 149;
    const float* hr = h2M + (size_t)m * 1024;
    float s = b3[oc];
#pragma unroll 8
    for (int k = 0; k < 1024; ++k) s = fmaf(hr[k], w3[k * 150 + oc], s);
    if (o < 150) out[m * 150 + o] = s;
}

// ---------------------------------------------------------------------------
extern "C" void kernel_launch(void* const* d_in, const int* in_sizes, int n_in,
                              void* d_out, int out_size, void* d_ws, size_t ws_size,
                              hipStream_t stream) {
    const float* X    = (const float*)d_in[0];
    const float* c1w1 = (const float*)d_in[1];
    const float* c1b1 = (const float*)d_in[2];
    const float* c1w2 = (const float*)d_in[3];
    const float* c1b2 = (const float*)d_in[4];
    const float* a1W  = (const float*)d_in[5];
    const float* a1b  = (const float*)d_in[6];
    const float* c2w1 = (const float*)d_in[7];
    const float* c2b1 = (const float*)d_in[8];
    const float* c2w2 = (const float*)d_in[9];
    const float* c2b2 = (const float*)d_in[10];
    const float* a2W  = (const float*)d_in[11];
    const float* a2b  = (const float*)d_in[12];
    const float* c3w1 = (const float*)d_in[13];
    const float* c3b1 = (const float*)d_in[14];
    const float* c3w2 = (const float*)d_in[15];
    const float* c3b2 = (const float*)d_in[16];
    const float* a3W  = (const float*)d_in[17];
    const float* a3b  = (const float*)d_in[18];
    const float* fc1w = (const float*)d_in[19];
    const float* fc1b = (const float*)d_in[20];
    const float* fc2w = (const float*)d_in[21];
    const float* fc2b = (const float*)d_in[22];
    const float* fc3w = (const float*)d_in[23];
    const float* fc3b = (const float*)d_in[24];

    float* ws  = (float*)d_ws;
    float* x1p = ws;                       // [0, 10.24M)
    float* x2p = ws + 10240000;            // [10.24M, 14.336M)
    float* x3p = ws + 14336000;            // [14.336M, 16.384M)
    float* e1  = ws + 16384000;            // [16.384M, 17.984M)
    float* e2  = ws + 17984000;
    float* e3  = ws + 18304000;
    float* z   = ws + 18368000;            // [18.368M, 25.536M)  dead after k_zt
    float* zT  = ws + 25536000;            // [25.536M, 34.752M)  live through k_gemm1
    float* p1  = ws;                       // 125*65536 = 8.192M floats
    float* pp  = ws + 16384000;            // 81,920 (old e1, dead)
    float* h1T = ws + 16600000;            // 65,536
    float* p2  = ws + 16700000;            // 64*1024*64 = 4.19M (ends 20.9M)
    float* h2M = ws + 21000000;            // 65,536

    k_s1<<<5000, 256, 0, stream>>>(X, c1w1, c1b1, c1w2, c1b2, a1W, a1b, x1p, e1);
    k_t1<<<3200, 64, 0, stream>>>(e1, X, c1w1, c1b1, c1w2, c1b2, z);
    k_s2<<<1000, 256, 0, stream>>>(x1p, c2w1, c2b1, c2w2, c2b2, a2W, a2b, x2p, e2);
    k_t2<<<3200, 64, 0, stream>>>(e2, x1p, c2w1, c2b1, c2w2, c2b2, z);
    k_s3<<<1000, 256, 0, stream>>>(x2p, c3w1, c3b1, c3w2, c3b2, a3W, a3b, x3p, e3);
    k_t3<<<3200, 64, 0, stream>>>(e3, x2p, c3w1, c3b1, c3w2, c3b2, z);
    k_zt<<<1750, 256, 0, stream>>>(z, zT);
    k_xf<<<250, 256, 0, stream>>>(x3p, zT);

    k_gemm1<<<dim3(8, 125), 256, 0, stream>>>(zT, fc1w, p1);
    k_redA<<<320, 256, 0, stream>>>(p1, pp);
    k_redB<<<64, 256, 0, stream>>>(pp, fc1b, h1T);
    k_gemm<<<dim3(4, 64), 256, 0, stream>>>(h1T, fc2w, p2, 1024, 1024, 16);
    k_red<<<64, 256, 0, stream>>>(p2, fc2b, h2M, 1024, 64);
    k_fc3<<<64, 192, 0, stream>>>(h2M, fc3w, fc3b, (float*)d_out);
}

// Round 11
// 883.209 us; speedup vs baseline: 1.6747x; 1.1046x over previous
//
#include <hip/hip_runtime.h>
#include <math.h>

#define DEV __device__ __forceinline__
DEV float frelu(float x) { return x > 0.f ? x : 0.f; }

typedef float f4 __attribute__((ext_vector_type(4)));
typedef short bf16x8 __attribute__((ext_vector_type(8)));
typedef int   i2x  __attribute__((ext_vector_type(2)));

DEV unsigned pack_hi2(float a, float b) {
    return (__float_as_uint(b) & 0xFFFF0000u) | (__float_as_uint(a) >> 16);
}
DEV float hi_part(float a) {
    return __uint_as_float(__float_as_uint(a) & 0xFFFF0000u);
}

// DPP partial-sum: VALU-pipe cross-lane (no LDS). After shr1,2,4,8:
// lane15/31/47/63 hold their row-of-16 suffix sums; +bcast15 -> lane31/63
// hold 32-lane half sums; +bcast31 -> lane63 holds the 64-lane sum.
#define DPP_ADD(v, ctrl) \
    ((v) + __int_as_float(__builtin_amdgcn_update_dpp(0, __float_as_int(v), (ctrl), 0xf, 0xf, true)))

DEV float rdlane(float v, int l) {
    return __int_as_float(__builtin_amdgcn_readlane(__float_as_int(v), l));
}

// ===========================================================================
// Stage 1 (WREG): conv 3->32 relu -> conv 32->32 relu ; e1 raw ; pool5 -> x1p
// e-reduce via DPP (half-wave sum -> lane31/lane63).
// ===========================================================================
#define NG1 8
__global__ __launch_bounds__(256) void k_s1(
    const float* __restrict__ x,
    const float* __restrict__ w1, const float* __restrict__ b1,
    const float* __restrict__ w2, const float* __restrict__ b2,
    const float* __restrict__ aW, const float* __restrict__ ab,
    float* __restrict__ x1p, float* __restrict__ e1)
{
    __shared__ float v1s[4][2][32];
    int tid = threadIdx.x;
    int wv = tid >> 6, lane = tid & 63;
    int half = lane >> 5, o = lane & 31;
    int hs = blockIdx.x * 8 + wv * 2 + half;     // 40000 half-slots

    float W1c0 = w1[o], W1c1 = w1[32 + o], W1c2 = w1[64 + o], B1 = b1[o];
    float W2[32];
#pragma unroll
    for (int i = 0; i < 32; ++i) W2[i] = w2[i * 32 + o];
    float B2 = b2[o];
    float* vs = &v1s[wv][half][0];

#pragma unroll 1
    for (int i = 0; i < NG1; ++i) {
        int g = hs * NG1 + i;                    // 0..319999
        int b = g / 5000, r = g % 5000, h = r / 100, pw = r % 100;
        float AWo = aW[h * 32 + o];
        const float* xrow = x + (size_t)((b * 50 + h) * 500) * 3;
        float vmax = 0.f;
#pragma unroll 1
        for (int j = 0; j < 5; ++j) {
            int w = pw * 5 + j;
            float x0 = xrow[w * 3 + 0], x1v = xrow[w * 3 + 1], x2v = xrow[w * 3 + 2];
            float v1 = frelu(fmaf(x0, W1c0, fmaf(x1v, W1c1, fmaf(x2v, W1c2, B1))));
            vs[o] = v1;
            float a2 = B2;
#pragma unroll
            for (int q = 0; q < 32; q += 4) {
                float4 v4 = *(const float4*)&vs[q];
                a2 = fmaf(v4.x, W2[q + 0], a2);
                a2 = fmaf(v4.y, W2[q + 1], a2);
                a2 = fmaf(v4.z, W2[q + 2], a2);
                a2 = fmaf(v4.w, W2[q + 3], a2);
            }
            float t = frelu(a2);
            vmax = fmaxf(vmax, t);
            float ep = t * AWo;
            ep = DPP_ADD(ep, 0x111);             // row_shr:1
            ep = DPP_ADD(ep, 0x112);             // row_shr:2
            ep = DPP_ADD(ep, 0x114);             // row_shr:4
            ep = DPP_ADD(ep, 0x118);             // row_shr:8
            ep = DPP_ADD(ep, 0x142);             // row_bcast15
            if (o == 31) e1[(b * 50 + h) * 500 + w] = ep + ab[h * 500 + w];
        }
        x1p[(size_t)g * 32 + o] = vmax;
    }
}

// ===========================================================================
// Stage 2 (WREG): conv 32->64 relu -> conv 64->64 relu ; e2 raw ; pool5
// e-reduce via DPP (64-lane sum -> lane63).
// ===========================================================================
#define NG2 16
__global__ __launch_bounds__(256) void k_s2(
    const float* __restrict__ x1p,
    const float* __restrict__ w1, const float* __restrict__ b1,
    const float* __restrict__ w2, const float* __restrict__ b2,
    const float* __restrict__ aW, const float* __restrict__ ab,
    float* __restrict__ x2p, float* __restrict__ e2)
{
    __shared__ float v1s[4][64];
    int tid = threadIdx.x;
    int wv = tid >> 6, o = tid & 63;
    int slot = blockIdx.x * 4 + wv;              // 4000 slots

    float W1[32];
#pragma unroll
    for (int i = 0; i < 32; ++i) W1[i] = w1[i * 64 + o];
    float W2[64];
#pragma unroll
    for (int i = 0; i < 64; ++i) W2[i] = w2[i * 64 + o];
    float B1 = b1[o], B2 = b2[o];
    float* vs = &v1s[wv][0];

#pragma unroll 1
    for (int i = 0; i < NG2; ++i) {
        int g = slot * NG2 + i;                  // 0..63999
        int b = g / 1000, r = g % 1000, h = r / 20, pw = r % 20;
        float AWo = aW[h * 64 + o];
        float vmax = 0.f;
#pragma unroll 1
        for (int j = 0; j < 5; ++j) {
            int w = pw * 5 + j;
            const float* in = x1p + (size_t)((b * 50 + h) * 100 + w) * 32;
            float a1 = B1;
#pragma unroll
            for (int q = 0; q < 32; q += 4) {
                float4 a4 = *(const float4*)&in[q];
                a1 = fmaf(a4.x, W1[q + 0], a1);
                a1 = fmaf(a4.y, W1[q + 1], a1);
                a1 = fmaf(a4.z, W1[q + 2], a1);
                a1 = fmaf(a4.w, W1[q + 3], a1);
            }
            vs[o] = frelu(a1);
            float a2 = B2;
#pragma unroll
            for (int q = 0; q < 64; q += 4) {
                float4 v4 = *(const float4*)&vs[q];
                a2 = fmaf(v4.x, W2[q + 0], a2);
                a2 = fmaf(v4.y, W2[q + 1], a2);
                a2 = fmaf(v4.z, W2[q + 2], a2);
                a2 = fmaf(v4.w, W2[q + 3], a2);
            }
            float t = frelu(a2);
            vmax = fmaxf(vmax, t);
            float ep = t * AWo;
            ep = DPP_ADD(ep, 0x111);
            ep = DPP_ADD(ep, 0x112);
            ep = DPP_ADD(ep, 0x114);
            ep = DPP_ADD(ep, 0x118);
            ep = DPP_ADD(ep, 0x142);             // row_bcast15
            ep = DPP_ADD(ep, 0x143);             // row_bcast31
            if (o == 63) e2[(b * 50 + h) * 100 + w] = ep + ab[h * 100 + w];
        }
        x2p[(size_t)g * 64 + o] = vmax;
    }
}

// ===========================================================================
// Stage 3 (WREG, split accumulators): conv 64->128 -> conv 128->128 ; e3 raw
// e-reduce via DPP per wave (lane63), epart combine unchanged.
// ===========================================================================
#define NG3 8
__global__ __launch_bounds__(256) void k_s3(
    const float* __restrict__ x2p,
    const float* __restrict__ w1, const float* __restrict__ b1,
    const float* __restrict__ w2, const float* __restrict__ b2,
    const float* __restrict__ aW, const float* __restrict__ ab,
    float* __restrict__ x3p, float* __restrict__ e3)
{
    __shared__ float v1s[2][128];
    __shared__ float epart[2][2];
    int tid = threadIdx.x;
    int wv = tid >> 6, lane = tid & 63;
    int slot = wv >> 1, oh = wv & 1;
    int o = oh * 64 + lane;
    int gs = blockIdx.x * 2 + slot;              // 2000 slots

    float W1[64];
#pragma unroll
    for (int i = 0; i < 64; ++i) W1[i] = w1[i * 128 + o];
    float W2[128];
#pragma unroll
    for (int i = 0; i < 128; ++i) W2[i] = w2[i * 128 + o];
    float B1 = b1[o], B2 = b2[o];

#pragma unroll 1
    for (int i = 0; i < NG3; ++i) {
        int g = gs * NG3 + i;                    // 0..15999
        int b = g / 250, r = g % 250, h = r / 5, pw = r % 5;
        float AWo = aW[h * 128 + o];
        float vmax = 0.f;
#pragma unroll 1
        for (int j = 0; j < 4; ++j) {
            int w = pw * 4 + j;
            const float* in = x2p + (size_t)((b * 50 + h) * 20 + w) * 64;
            float a1a = B1, a1b = 0.f;
#pragma unroll
            for (int q = 0; q < 64; q += 8) {
                float4 a4 = *(const float4*)&in[q];
                float4 b4 = *(const float4*)&in[q + 4];
                a1a = fmaf(a4.x, W1[q + 0], a1a);
                a1b = fmaf(a4.y, W1[q + 1], a1b);
                a1a = fmaf(a4.z, W1[q + 2], a1a);
                a1b = fmaf(a4.w, W1[q + 3], a1b);
                a1a = fmaf(b4.x, W1[q + 4], a1a);
                a1b = fmaf(b4.y, W1[q + 5], a1b);
                a1a = fmaf(b4.z, W1[q + 6], a1a);
                a1b = fmaf(b4.w, W1[q + 7], a1b);
            }
            v1s[slot][o] = frelu(a1a + a1b);
            __syncthreads();
            float a2a = B2, a2b = 0.f, a2c = 0.f, a2d = 0.f;
#pragma unroll
            for (int q = 0; q < 128; q += 8) {
                float4 a4 = *(const float4*)&v1s[slot][q];
                float4 b4 = *(const float4*)&v1s[slot][q + 4];
                a2a = fmaf(a4.x, W2[q + 0], a2a);
                a2b = fmaf(a4.y, W2[q + 1], a2b);
                a2c = fmaf(a4.z, W2[q + 2], a2c);
                a2d = fmaf(a4.w, W2[q + 3], a2d);
                a2a = fmaf(b4.x, W2[q + 4], a2a);
                a2b = fmaf(b4.y, W2[q + 5], a2b);
                a2c = fmaf(b4.z, W2[q + 6], a2c);
                a2d = fmaf(b4.w, W2[q + 7], a2d);
            }
            float t = frelu((a2a + a2b) + (a2c + a2d));
            vmax = fmaxf(vmax, t);
            float ep = t * AWo;
            ep = DPP_ADD(ep, 0x111);
            ep = DPP_ADD(ep, 0x112);
            ep = DPP_ADD(ep, 0x114);
            ep = DPP_ADD(ep, 0x118);
            ep = DPP_ADD(ep, 0x142);
            ep = DPP_ADD(ep, 0x143);
            if (lane == 63) epart[slot][oh] = ep;
            __syncthreads();
            if (lane == 63 && oh == 0)
                e3[(b * 50 + h) * 20 + w] = epart[slot][0] + epart[slot][1] + ab[h * 20 + w];
        }
        x3p[(size_t)g * 128 + o] = vmax;
    }
}

// ===========================================================================
// Top-k (k=10, value desc, tie -> lower index) + feature recompute.
// Gather broadcasts via v_readlane (VALU) instead of __shfl (LDS bpermute).
// ===========================================================================
__global__ __launch_bounds__(64) void k_t1(
    const float* __restrict__ e1, const float* __restrict__ x,
    const float* __restrict__ w1, const float* __restrict__ b1,
    const float* __restrict__ w2, const float* __restrict__ b2,
    float* __restrict__ z)
{
    int blk = blockIdx.x; int b = blk / 50; int h = blk % 50;
    int lane = threadIdx.x;
    const float* er = e1 + (b * 50 + h) * 500;
    float ev0 = er[lane];
    float ev1 = er[64 + lane];
    float ev2 = er[128 + lane];
    float ev3 = er[192 + lane];
    float ev4 = er[256 + lane];
    float ev5 = er[320 + lane];
    float ev6 = er[384 + lane];
    float ev7 = (448 + lane < 500) ? er[448 + lane] : -1e30f;

    for (int k = 0; k < 10; ++k) {
        float bv = ev0; int bi = lane;
        if (ev1 > bv) { bv = ev1; bi = 64 + lane; }
        if (ev2 > bv) { bv = ev2; bi = 128 + lane; }
        if (ev3 > bv) { bv = ev3; bi = 192 + lane; }
        if (ev4 > bv) { bv = ev4; bi = 256 + lane; }
        if (ev5 > bv) { bv = ev5; bi = 320 + lane; }
        if (ev6 > bv) { bv = ev6; bi = 384 + lane; }
        if (ev7 > bv) { bv = ev7; bi = 448 + lane; }
#pragma unroll
        for (int d = 1; d < 64; d <<= 1) {
            float ov = __shfl_xor(bv, d, 64); int oi = __shfl_xor(bi, d, 64);
            if (ov > bv || (ov == bv && oi < bi)) { bv = ov; bi = oi; }
        }
        bool me = (bi & 63) == lane; int cs = bi >> 6;
        if (me && cs == 0) ev0 = -1e30f;
        if (me && cs == 1) ev1 = -1e30f;
        if (me && cs == 2) ev2 = -1e30f;
        if (me && cs == 3) ev3 = -1e30f;
        if (me && cs == 4) ev4 = -1e30f;
        if (me && cs == 5) ev5 = -1e30f;
        if (me && cs == 6) ev6 = -1e30f;
        if (me && cs == 7) ev7 = -1e30f;

        const float* px = x + (size_t)((b * 50 + h) * 500 + bi) * 3;
        float x0 = px[0], x1v = px[1], x2v = px[2];
        int o = lane & 31;
        float v1 = frelu(fmaf(x0, w1[o], fmaf(x1v, w1[32 + o], fmaf(x2v, w1[64 + o], b1[o]))));
        float v2 = b2[o];
#pragma unroll 8
        for (int i = 0; i < 32; ++i) v2 = fmaf(rdlane(v1, i), w2[i * 32 + o], v2);
        if (lane < 32) z[(size_t)b * 112000 + h * 320 + k * 32 + o] = frelu(v2);
    }
}

__global__ __launch_bounds__(64) void k_t2(
    const float* __restrict__ e2, const float* __restrict__ x1p,
    const float* __restrict__ w1, const float* __restrict__ b1,
    const float* __restrict__ w2, const float* __restrict__ b2,
    float* __restrict__ z)
{
    int blk = blockIdx.x; int b = blk / 50; int h = blk % 50;
    int lane = threadIdx.x;
    const float* er = e2 + (b * 50 + h) * 100;
    float ev0 = er[lane];
    float ev1 = (64 + lane < 100) ? er[64 + lane] : -1e30f;

    for (int k = 0; k < 10; ++k) {
        float bv = ev0; int bi = lane;
        if (ev1 > bv) { bv = ev1; bi = 64 + lane; }
#pragma unroll
        for (int d = 1; d < 64; d <<= 1) {
            float ov = __shfl_xor(bv, d, 64); int oi = __shfl_xor(bi, d, 64);
            if (ov > bv || (ov == bv && oi < bi)) { bv = ov; bi = oi; }
        }
        bool me = (bi & 63) == lane; int cs = bi >> 6;
        if (me && cs == 0) ev0 = -1e30f;
        if (me && cs == 1) ev1 = -1e30f;

        const float* in = x1p + (size_t)((b * 50 + h) * 100 + bi) * 32;
        float v1p0 = b1[lane], v1p1 = 0.f;
#pragma unroll 8
        for (int i = 0; i < 32; i += 2) {
            v1p0 = fmaf(in[i], w1[i * 64 + lane], v1p0);
            v1p1 = fmaf(in[i + 1], w1[(i + 1) * 64 + lane], v1p1);
        }
        float v1 = frelu(v1p0 + v1p1);
        float v2p0 = b2[lane], v2p1 = 0.f;
#pragma unroll 8
        for (int i = 0; i < 64; i += 2) {
            v2p0 = fmaf(rdlane(v1, i), w2[i * 64 + lane], v2p0);
            v2p1 = fmaf(rdlane(v1, i + 1), w2[(i + 1) * 64 + lane], v2p1);
        }
        z[(size_t)b * 112000 + 16000 + h * 640 + k * 64 + lane] = frelu(v2p0 + v2p1);
    }
}

__global__ __launch_bounds__(64) void k_t3(
    const float* __restrict__ e3, const float* __restrict__ x2p,
    const float* __restrict__ w1, const float* __restrict__ b1,
    const float* __restrict__ w2, const float* __restrict__ b2,
    float* __restrict__ z)
{
    int blk = blockIdx.x; int b = blk / 50; int h = blk % 50;
    int lane = threadIdx.x;
    const float* er = e3 + (b * 50 + h) * 20;
    float ev0 = (lane < 20) ? er[lane] : -1e30f;

    for (int k = 0; k < 10; ++k) {
        float bv = ev0; int bi = lane;
#pragma unroll
        for (int d = 1; d < 64; d <<= 1) {
            float ov = __shfl_xor(bv, d, 64); int oi = __shfl_xor(bi, d, 64);
            if (ov > bv || (ov == bv && oi < bi)) { bv = ov; bi = oi; }
        }
        if (bi == lane) ev0 = -1e30f;
        const float* in = x2p + (size_t)((b * 50 + h) * 20 + bi) * 64;
        float v1a0 = b1[lane], v1a1 = 0.f, v1b0 = b1[lane + 64], v1b1 = 0.f;
#pragma unroll 8
        for (int i = 0; i < 64; i += 2) {
            float a0 = in[i], a1 = in[i + 1];
            v1a0 = fmaf(a0, w1[i * 128 + lane], v1a0);
            v1b0 = fmaf(a0, w1[i * 128 + lane + 64], v1b0);
            v1a1 = fmaf(a1, w1[(i + 1) * 128 + lane], v1a1);
            v1b1 = fmaf(a1, w1[(i + 1) * 128 + lane + 64], v1b1);
        }
        float v1a = frelu(v1a0 + v1a1), v1b = frelu(v1b0 + v1b1);
        float v2a0 = b2[lane], v2a1 = 0.f, v2b0 = b2[lane + 64], v2b1 = 0.f;
#pragma unroll 8
        for (int i = 0; i < 64; i += 2) {
            float s0 = rdlane(v1a, i), s1 = rdlane(v1a, i + 1);
            v2a0 = fmaf(s0, w2[i * 128 + lane], v2a0);
            v2b0 = fmaf(s0, w2[i * 128 + lane + 64], v2b0);
            v2a1 = fmaf(s1, w2[(i + 1) * 128 + lane], v2a1);
            v2b1 = fmaf(s1, w2[(i + 1) * 128 + lane + 64], v2b1);
        }
#pragma unroll 8
        for (int i = 0; i < 64; i += 2) {
            float s0 = rdlane(v1b, i), s1 = rdlane(v1b, i + 1);
            v2a0 = fmaf(s0, w2[(i + 64) * 128 + lane], v2a0);
            v2b0 = fmaf(s0, w2[(i + 64) * 128 + lane + 64], v2b0);
            v2a1 = fmaf(s1, w2[(i + 65) * 128 + lane], v2a1);
            v2b1 = fmaf(s1, w2[(i + 65) * 128 + lane + 64], v2b1);
        }
        size_t base = (size_t)b * 112000 + 48000 + h * 1280 + k * 128;
        z[base + lane] = frelu(v2a0 + v2a1);
        z[base + lane + 64] = frelu(v2b0 + v2b1);
    }
}

// ===========================================================================
// k_zt: transpose z[m][f] (f<112000) -> zT[f][m]
// ===========================================================================
__global__ __launch_bounds__(256) void k_zt(const float* __restrict__ z, float* __restrict__ zT)
{
    __shared__ float t[64][65];
    int f0 = blockIdx.x * 64;                // 1750 blocks
    int tid = threadIdx.x;
    int fl = tid & 63, q = tid >> 6;
#pragma unroll
    for (int rr = 0; rr < 16; ++rr) {
        int m = q * 16 + rr;
        t[m][fl] = z[(size_t)m * 112000 + f0 + fl];
    }
    __syncthreads();
    int m2 = tid & 63;
#pragma unroll
    for (int rr = 0; rr < 16; ++rr) {
        int fl2 = q * 16 + rr;
        zT[(size_t)(f0 + fl2) * 64 + m2] = t[m2][fl2];
    }
}

// ===========================================================================
// k_xf: x3p (B,H,5,128) -> zT rows 112000 + c*250 + h*5 + pw, layout [f][m]
// ===========================================================================
__global__ __launch_bounds__(256) void k_xf(const float* __restrict__ x3p, float* __restrict__ zT)
{
    __shared__ float t[64][129];
    int blk = blockIdx.x;                    // 250
    int h = blk / 5, pw = blk % 5;
    int tid = threadIdx.x;
    for (int idx = tid; idx < 64 * 128; idx += 256) {
        int m = idx >> 7, c = idx & 127;
        t[m][c] = x3p[(size_t)((m * 50 + h) * 5 + pw) * 128 + c];
    }
    __syncthreads();
    for (int idx = tid; idx < 64 * 128; idx += 256) {
        int c = idx >> 6, m = idx & 63;
        zT[(size_t)(112000 + c * 250 + h * 5 + pw) * 64 + m] = t[m][c];
    }
}

// ===========================================================================
// fc1 GEMM — bf16-split MFMA (16x16x32) (unchanged from R10, verified).
// ===========================================================================
__global__ __launch_bounds__(256, 3) void k_gemm1(
    const float* __restrict__ AT, const float* __restrict__ W,
    float* __restrict__ part)
{
    __shared__ char smem[24576];
    const int t = threadIdx.x;
    const int lane = t & 63;
    const int wv = t >> 6;
    const int n0 = blockIdx.x << 7;
    const int kc = blockIdx.y;

    const int nw = t & 127, kqi = t >> 7;
    const int ma = t & 63,  kqa = t >> 6;

    int wadrW[4];
#pragma unroll
    for (int q = 0; q < 4; ++q)
        wadrW[q] = nw * 64 + (((kqi * 2 + (q >> 1)) ^ (nw & 3)) << 4) + ((q & 1) << 3);
    int wadrA[2];
#pragma unroll
    for (int q = 0; q < 2; ++q)
        wadrA[q] = 16384 + ma * 64 + ((kqa ^ (ma & 3)) << 4) + (q << 3);

    const int c = lane & 15, hi = lane >> 4;
    int rW[2], rA[4];
#pragma unroll
    for (int i = 0; i < 2; ++i) {
        int nl = (2 * wv + i) * 16 + c;
        rW[i] = nl * 64 + ((hi ^ (c & 3)) << 4);
    }
#pragma unroll
    for (int mf = 0; mf < 4; ++mf) {
        int ml = mf * 16 + c;
        rA[mf] = 16384 + ml * 64 + ((hi ^ (c & 3)) << 4);
    }

    f4 acc[2][4];
#pragma unroll
    for (int i = 0; i < 2; ++i)
#pragma unroll
        for (int mf = 0; mf < 4; ++mf) acc[i][mf] = (f4)0.f;

    const float* Wp = W + ((size_t)kc * 1152 + kqi * 16) * 1024 + (n0 + nw);
    const float* Ap = AT + ((size_t)kc * 1152 + kqa * 8) * 64 + ma;

    float gw[16], ga[8];
#pragma unroll
    for (int j = 0; j < 16; ++j) gw[j] = Wp[(size_t)j * 1024];
#pragma unroll
    for (int j = 0; j < 8; ++j) ga[j] = Ap[j * 64];
    Wp += 32768; Ap += 2048;

#pragma unroll 1
    for (int cc = 0; cc < 36; ++cc) {
        i2x whv[4], wlv[4], ahv[2], alv[2];
#pragma unroll
        for (int q = 0; q < 4; ++q) {
            float x0 = gw[q * 4 + 0], x1 = gw[q * 4 + 1];
            float x2 = gw[q * 4 + 2], x3 = gw[q * 4 + 3];
            whv[q].x = pack_hi2(x0, x1); whv[q].y = pack_hi2(x2, x3);
            float l0 = x0 - hi_part(x0), l1 = x1 - hi_part(x1);
            float l2 = x2 - hi_part(x2), l3 = x3 - hi_part(x3);
            wlv[q].x = pack_hi2(l0, l1); wlv[q].y = pack_hi2(l2, l3);
        }
#pragma unroll
        for (int q = 0; q < 2; ++q) {
            float x0 = ga[q * 4 + 0], x1 = ga[q * 4 + 1];
            float x2 = ga[q * 4 + 2], x3 = ga[q * 4 + 3];
            ahv[q].x = pack_hi2(x0, x1); ahv[q].y = pack_hi2(x2, x3);
            float l0 = x0 - hi_part(x0), l1 = x1 - hi_part(x1);
            float l2 = x2 - hi_part(x2), l3 = x3 - hi_part(x3);
            alv[q].x = pack_hi2(l0, l1); alv[q].y = pack_hi2(l2, l3);
        }
        __syncthreads();
#pragma unroll
        for (int q = 0; q < 4; ++q) {
            *(i2x*)(smem + wadrW[q]) = whv[q];
            *(i2x*)(smem + wadrW[q] + 8192) = wlv[q];
        }
#pragma unroll
        for (int q = 0; q < 2; ++q) {
            *(i2x*)(smem + wadrA[q]) = ahv[q];
            *(i2x*)(smem + wadrA[q] + 4096) = alv[q];
        }
        if (cc < 35) {
#pragma unroll
            for (int j = 0; j < 16; ++j) gw[j] = Wp[(size_t)j * 1024];
#pragma unroll
            for (int j = 0; j < 8; ++j) ga[j] = Ap[j * 64];
            Wp += 32768; Ap += 2048;
        }
        __syncthreads();

        bf16x8 fwh[2], fwl[2], fah[4], fal[4];
#pragma unroll
        for (int i = 0; i < 2; ++i) {
            fwh[i] = *(const bf16x8*)(smem + rW[i]);
            fwl[i] = *(const bf16x8*)(smem + rW[i] + 8192);
        }
#pragma unroll
        for (int mf = 0; mf < 4; ++mf) {
            fah[mf] = *(const bf16x8*)(smem + rA[mf]);
            fal[mf] = *(const bf16x8*)(smem + rA[mf] + 4096);
        }
#pragma unroll
        for (int i = 0; i < 2; ++i)
#pragma unroll
            for (int mf = 0; mf < 4; ++mf) {
                acc[i][mf] = __builtin_amdgcn_mfma_f32_16x16x32_bf16(fwh[i], fah[mf], acc[i][mf], 0, 0, 0);
                acc[i][mf] = __builtin_amdgcn_mfma_f32_16x16x32_bf16(fwh[i], fal[mf], acc[i][mf], 0, 0, 0);
                acc[i][mf] = __builtin_amdgcn_mfma_f32_16x16x32_bf16(fwl[i], fah[mf], acc[i][mf], 0, 0, 0);
            }
    }

    float* pb = part + ((size_t)kc * 1024 + n0) * 64;
#pragma unroll
    for (int i = 0; i < 2; ++i) {
        int nf = 2 * wv + i;
#pragma unroll
        for (int mf = 0; mf < 4; ++mf) {
#pragma unroll
            for (int q = 0; q < 4; ++q) {
                int n = nf * 16 + hi * 4 + q;
                int m = mf * 16 + c;
                pb[(size_t)n * 64 + m] = acc[i][mf][q];
            }
        }
    }
}

// ===========================================================================
// Generic skinny GEMM (fc2): AT[k][64] uniform (s_load), W[k][n] coalesced.
// ===========================================================================
__global__ __launch_bounds__(256) void k_gemm(
    const float* __restrict__ AT, const float* __restrict__ W,
    float* __restrict__ part, int K, int N, int KC)
{
    int n = blockIdx.x * 256 + threadIdx.x;
    int kc = blockIdx.y;
    int k0 = kc * KC;
    int k1 = k0 + KC; if (k1 > K) k1 = K;
    float acc[64];
#pragma unroll
    for (int m = 0; m < 64; ++m) acc[m] = 0.f;
#pragma unroll 2
    for (int k = k0; k < k1; ++k) {
        float wv = W[(size_t)k * N + n];
        const float4* Ak4 = (const float4*)(AT + (size_t)k * 64);
#pragma unroll
        for (int mq = 0; mq < 16; ++mq) {
            float4 a = Ak4[mq];
            acc[4 * mq + 0] = fmaf(a.x, wv, acc[4 * mq + 0]);
            acc[4 * mq + 1] = fmaf(a.y, wv, acc[4 * mq + 1]);
            acc[4 * mq + 2] = fmaf(a.z, wv, acc[4 * mq + 2]);
            acc[4 * mq + 3] = fmaf(a.w, wv, acc[4 * mq + 3]);
        }
    }
    float4* p4 = (float4*)(part + ((size_t)kc * N + n) * 64);
#pragma unroll
    for (int mq = 0; mq < 16; ++mq)
        p4[mq] = make_float4(acc[4 * mq], acc[4 * mq + 1], acc[4 * mq + 2], acc[4 * mq + 3]);
}

// ===========================================================================
// fc1 reduce: part[kc][n][m] (kc=0..124) -> pp[s][n][m] (s=0..4, 25 each)
// ===========================================================================
__global__ __launch_bounds__(256) void k_redA(
    const float* __restrict__ part, float* __restrict__ pp)
{
    int id = blockIdx.x * 256 + threadIdx.x;  // 81920
    int r = id & 16383; int s = id >> 14;     // s in [0,5)
    const f4* p = (const f4*)part;
    f4 v = (f4)0.f;
#pragma unroll 5
    for (int cidx = s * 25; cidx < s * 25 + 25; ++cidx)
        v += p[(size_t)cidx * 16384 + r];
    ((f4*)pp)[(size_t)s * 16384 + r] = v;
}

// pp[s][n][m] -> h1T[n][m] (+bias, relu).
__global__ __launch_bounds__(256) void k_redB(
    const float* __restrict__ pp, const float* __restrict__ bias,
    float* __restrict__ h1T)
{
    int id = blockIdx.x * 256 + threadIdx.x;  // 16384
    int mq = id & 15, n = id >> 4;
    const f4* p = (const f4*)pp;
    f4 s = (f4)0.f;
#pragma unroll
    for (int cidx = 0; cidx < 5; ++cidx) s += p[(size_t)cidx * 16384 + id];
    float bv = bias[n];
    s += bv;
    s.x = frelu(s.x); s.y = frelu(s.y); s.z = frelu(s.z); s.w = frelu(s.w);
    *(f4*)(h1T + (size_t)n * 64 + mq * 4) = s;
}

// Reduce fc2 partials; write M-MAJOR out[m][n].
__global__ __launch_bounds__(256) void k_red(
    const float* __restrict__ part, const float* __restrict__ bias,
    float* __restrict__ outM, int N, int C)
{
    int id = blockIdx.x * 256 + threadIdx.x;  // N*16
    int mq = id & 15, n = id >> 4;
    f4 s = (f4)0.f;
    for (int cidx = 0; cidx < C; ++cidx)
        s += *(const f4*)(part + ((size_t)cidx * N + n) * 64 + mq * 4);
    float bv = bias[n];
    s += bv;
    outM[(size_t)(mq * 4 + 0) * N + n] = s.x;
    outM[(size_t)(mq * 4 + 1) * N + n] = s.y;
    outM[(size_t)(mq * 4 + 2) * N + n] = s.z;
    outM[(size_t)(mq * 4 + 3) * N + n] = s.w;
}

// ===========================================================================
// fc3: block = one m row; h2M[m][k] wave-uniform (s_load broadcast).
// ===========================================================================
__global__ __launch_bounds__(192) void k_fc3(
    const float* __restrict__ h2M, const float* __restrict__ w3,
    const float* __restrict__ b3, float* __restrict__ out)
{
    int m = blockIdx.x;                      // 64
    int o = threadIdx.x;                     // 192, active < 150
    int oc = o < 150 ? o : 149;
    const float* hr = h2M + (size_t)m * 1024;
    float s = b3[oc];
#pragma unroll 8
    for (int k = 0; k < 1024; ++k) s = fmaf(hr[k], w3[k * 150 + oc], s);
    if (o < 150) out[m * 150 + o] = s;
}

// ---------------------------------------------------------------------------
extern "C" void kernel_launch(void* const* d_in, const int* in_sizes, int n_in,
                              void* d_out, int out_size, void* d_ws, size_t ws_size,
                              hipStream_t stream) {
    const float* X    = (const float*)d_in[0];
    const float* c1w1 = (const float*)d_in[1];
    const float* c1b1 = (const float*)d_in[2];
    const float* c1w2 = (const float*)d_in[3];
    const float* c1b2 = (const float*)d_in[4];
    const float* a1W  = (const float*)d_in[5];
    const float* a1b  = (const float*)d_in[6];
    const float* c2w1 = (const float*)d_in[7];
    const float* c2b1 = (const float*)d_in[8];
    const float* c2w2 = (const float*)d_in[9];
    const float* c2b2 = (const float*)d_in[10];
    const float* a2W  = (const float*)d_in[11];
    const float* a2b  = (const float*)d_in[12];
    const float* c3w1 = (const float*)d_in[13];
    const float* c3b1 = (const float*)d_in[14];
    const float* c3w2 = (const float*)d_in[15];
    const float* c3b2 = (const float*)d_in[16];
    const float* a3W  = (const float*)d_in[17];
    const float* a3b  = (const float*)d_in[18];
    const float* fc1w = (const float*)d_in[19];
    const float* fc1b = (const float*)d_in[20];
    const float* fc2w = (const float*)d_in[21];
    const float* fc2b = (const float*)d_in[22];
    const float* fc3w = (const float*)d_in[23];
    const float* fc3b = (const float*)d_in[24];

    float* ws  = (float*)d_ws;
    float* x1p = ws;                       // [0, 10.24M)
    float* x2p = ws + 10240000;            // [10.24M, 14.336M)
    float* x3p = ws + 14336000;            // [14.336M, 16.384M)
    float* e1  = ws + 16384000;            // [16.384M, 17.984M)
    float* e2  = ws + 17984000;
    float* e3  = ws + 18304000;
    float* z   = ws + 18368000;            // [18.368M, 25.536M)  dead after k_zt
    float* zT  = ws + 25536000;            // [25.536M, 34.752M)  live through k_gemm1
    float* p1  = ws;                       // 125*65536 = 8.192M floats
    float* pp  = ws + 16384000;            // 81,920 (old e1, dead)
    float* h1T = ws + 16600000;            // 65,536
    float* p2  = ws + 16700000;            // 64*1024*64 = 4.19M (ends 20.9M)
    float* h2M = ws + 21000000;            // 65,536

    k_s1<<<5000, 256, 0, stream>>>(X, c1w1, c1b1, c1w2, c1b2, a1W, a1b, x1p, e1);
    k_t1<<<3200, 64, 0, stream>>>(e1, X, c1w1, c1b1, c1w2, c1b2, z);
    k_s2<<<1000, 256, 0, stream>>>(x1p, c2w1, c2b1, c2w2, c2b2, a2W, a2b, x2p, e2);
    k_t2<<<3200, 64, 0, stream>>>(e2, x1p, c2w1, c2b1, c2w2, c2b2, z);
    k_s3<<<1000, 256, 0, stream>>>(x2p, c3w1, c3b1, c3w2, c3b2, a3W, a3b, x3p, e3);
    k_t3<<<3200, 64, 0, stream>>>(e3, x2p, c3w1, c3b1, c3w2, c3b2, z);
    k_zt<<<1750, 256, 0, stream>>>(z, zT);
    k_xf<<<250, 256, 0, stream>>>(x3p, zT);

    k_gemm1<<<dim3(8, 125), 256, 0, stream>>>(zT, fc1w, p1);
    k_redA<<<320, 256, 0, stream>>>(p1, pp);
    k_redB<<<64, 256, 0, stream>>>(pp, fc1b, h1T);
    k_gemm<<<dim3(4, 64), 256, 0, stream>>>(h1T, fc2w, p2, 1024, 1024, 16);
    k_red<<<64, 256, 0, stream>>>(p2, fc2b, h2M, 1024, 64);
    k_fc3<<<64, 192, 0, stream>>>(h2M, fc3w, fc3b, (float*)d_out);
}